// Round 4
// baseline (528.507 us; speedup 1.0000x reference)
//
#include <hip/hip_runtime.h>
#include <hip/hip_bf16.h>

#define N_NODES 20000
#define NEDGE   320000
#define DIM     128
#define NH      4
#define HD      512   // NH*DIM
#define LAYERS  3
#define EPS_RMS 1.1920929e-07f
#define SLOPE   0.2f

typedef __bf16 bf16_t;
typedef __bf16 bf16v8 __attribute__((ext_vector_type(8)));
typedef float  f32v4  __attribute__((ext_vector_type(4)));

__device__ __forceinline__ int clamp_node(int s) {
    return ((unsigned)s >= (unsigned)N_NODES) ? 0 : s;
}

// ---------------- dtype detection ----------------
// Float dtype: sample even 16-bit halfwords of x. bf16 N(0,1) data: exponent in
// [96,140] ~always. f32 data: even halfwords are low mantissa bits, ~18% hit.
__global__ void detect_f32_kernel(const unsigned short* __restrict__ x,
                                  int* __restrict__ isbf16) {
    __shared__ int cnt;
    if (threadIdx.x == 0) cnt = 0;
    __syncthreads();
    unsigned short h = x[2 * threadIdx.x];
    int e = (h >> 7) & 0xff;
    if (e >= 96 && e <= 140) atomicAdd(&cnt, 1);
    __syncthreads();
    if (threadIdx.x == 0) *isbf16 = (cnt >= 700) ? 1 : 0;
}

// Int dtype: int64 little-endian high words are all zero; int32 node ids are not.
__global__ void detect_int64_kernel(const int* __restrict__ ei, int* __restrict__ flag) {
    int t = threadIdx.x;
    if (ei[2 * t + 1] != 0) atomicAdd(flag, 1);
}

__device__ __forceinline__ int edge_src(const int* ei, int e, bool is64) {
    return clamp_node(is64 ? ei[2 * e] : ei[e]);
}
__device__ __forceinline__ int edge_dst(const int* ei, int e, bool is64) {
    return clamp_node(is64 ? ei[2 * NEDGE + 2 * e] : ei[NEDGE + e]);
}

// ---------------- input canonicalization (f32|bf16 -> bf16) ----------------

__global__ void convert_kernel(const void* __restrict__ in, bf16_t* __restrict__ out,
                               int n, const int* __restrict__ isbf16) {
    int i = blockIdx.x * blockDim.x + threadIdx.x;
    if (i >= n) return;
    if (*isbf16) {
        out[i] = ((const bf16_t*)in)[i];
    } else {
        out[i] = (bf16_t)((const float*)in)[i];
    }
}

// out[l][c][k] = in[l][k][c], with dtype conversion
__global__ void transpose_convert_kernel(const void* __restrict__ in, bf16_t* __restrict__ out,
                                         int K, int C, int L, const int* __restrict__ isbf16) {
    int idx = blockIdx.x * blockDim.x + threadIdx.x;
    int total = K * C * L;
    if (idx >= total) return;
    int l = idx / (K * C);
    int rem = idx - l * (K * C);
    int c = rem / K;
    int k = rem - c * K;
    size_t src = (size_t)l * K * C + (size_t)k * C + c;
    if (*isbf16) {
        out[idx] = ((const bf16_t*)in)[src];
    } else {
        out[idx] = (bf16_t)((const float*)in)[src];
    }
}

// ---------------- CSR build ----------------

__global__ void hist_kernel(const int* __restrict__ ei, int* __restrict__ deg,
                            const int* __restrict__ flag) {
    int e = blockIdx.x * blockDim.x + threadIdx.x;
    bool is64 = (*flag == 0);
    if (e < NEDGE) atomicAdd(&deg[edge_dst(ei, e, is64)], 1);
}

__global__ __launch_bounds__(1024) void scan_kernel(const int* __restrict__ deg,
                                                    int* __restrict__ row_ptr,
                                                    int* __restrict__ cursor) {
    __shared__ int buf[2][1024];
    __shared__ int carry;
    int tid = threadIdx.x;
    if (tid == 0) { carry = 0; row_ptr[0] = 0; }
    __syncthreads();
    for (int base = 0; base < N_NODES; base += 1024) {
        int idx = base + tid;
        int v = (idx < N_NODES) ? deg[idx] : 0;
        int cur = 0;
        buf[0][tid] = v;
        __syncthreads();
        for (int off = 1; off < 1024; off <<= 1) {
            int nv = buf[cur][tid];
            if (tid >= off) nv += buf[cur][tid - off];
            buf[1 - cur][tid] = nv;
            cur ^= 1;
            __syncthreads();
        }
        int incl = buf[cur][tid];
        int c = carry;
        if (idx < N_NODES) {
            row_ptr[idx + 1] = c + incl;
            cursor[idx] = c + incl - v;   // exclusive prefix = fill start
        }
        __syncthreads();
        if (tid == 1023) carry = c + buf[cur][1023];
        __syncthreads();
    }
}

__global__ void fill_kernel(const int* __restrict__ ei, int* __restrict__ cursor,
                            int* __restrict__ csr_src, const int* __restrict__ flag) {
    int e = blockIdx.x * blockDim.x + threadIdx.x;
    bool is64 = (*flag == 0);
    if (e < NEDGE) {
        int d = edge_dst(ei, e, is64);
        int pos = atomicAdd(&cursor[d], 1);
        if ((unsigned)pos < (unsigned)NEDGE) csr_src[pos] = edge_src(ei, e, is64);
    }
}

// ---------------- GEMM (one wave = 16 rows x 128 cols, K=128) ----------------
// EPI 0: store C (bf16)            (xp = x @ Wg)
// EPI 1: store relu(C+b) (bf16)    (h = relu(x@W1+b1))
// EPI 2: store rmsnorm(res+C+b) bf16   (ncols must be 128)
// EPI 3: store rmsnorm(res+C+b) f32    (final layer -> d_out)

template <int EPI>
__global__ __launch_bounds__(256) void gemm16(const bf16_t* __restrict__ A,
                                              const bf16_t* __restrict__ Bt,
                                              const bf16_t* __restrict__ bias,
                                              const bf16_t* __restrict__ res,
                                              const bf16_t* __restrict__ normw,
                                              void* __restrict__ Cout,
                                              int M, int ncols) {
    int unitsPerRow = ncols >> 7;
    int unit = (int)((blockIdx.x * blockDim.x + threadIdx.x) >> 6);
    int totalUnits = (M >> 4) * unitsPerRow;
    if (unit >= totalUnits) return;
    int lane = threadIdx.x & 63;
    int row16 = unit / unitsPerRow;
    int colbase = (unit - row16 * unitsPerRow) << 7;
    int m = lane & 15;
    int kq = lane >> 4;

    const bf16_t* Arow = A + (size_t)(row16 * 16 + m) * DIM + kq * 8;
    bf16v8 a[4];
#pragma unroll
    for (int ks = 0; ks < 4; ++ks)
        a[ks] = *reinterpret_cast<const bf16v8*>(Arow + ks * 32);

    f32v4 acc[8];
#pragma unroll
    for (int t = 0; t < 8; ++t) acc[t] = (f32v4){0.f, 0.f, 0.f, 0.f};

    const bf16_t* Bbase = Bt + (size_t)(colbase + m) * DIM + kq * 8;
#pragma unroll
    for (int ks = 0; ks < 4; ++ks) {
#pragma unroll
        for (int t = 0; t < 8; ++t) {
            bf16v8 b = *reinterpret_cast<const bf16v8*>(Bbase + (size_t)t * 16 * DIM + ks * 32);
            acc[t] = __builtin_amdgcn_mfma_f32_16x16x32_bf16(a[ks], b, acc[t], 0, 0, 0);
        }
    }

    int growbase = row16 * 16 + kq * 4;
    bf16_t* Cb = (bf16_t*)Cout;
    float*  Cf = (float*)Cout;
    if (EPI == 0) {
#pragma unroll
        for (int t = 0; t < 8; ++t) {
            int col = colbase + t * 16 + m;
#pragma unroll
            for (int r = 0; r < 4; ++r)
                Cb[(size_t)(growbase + r) * ncols + col] = (bf16_t)acc[t][r];
        }
    } else if (EPI == 1) {
#pragma unroll
        for (int t = 0; t < 8; ++t) {
            int col = colbase + t * 16 + m;
            float bv = (float)bias[col];
#pragma unroll
            for (int r = 0; r < 4; ++r) {
                float v = acc[t][r] + bv;
                v = v > 0.f ? v : 0.f;
                Cb[(size_t)(growbase + r) * ncols + col] = (bf16_t)v;
            }
        }
    } else {
        float vals[8][4];
        float ss[4] = {0.f, 0.f, 0.f, 0.f};
#pragma unroll
        for (int t = 0; t < 8; ++t) {
            int col = colbase + t * 16 + m;
            float bv = (float)bias[col];
#pragma unroll
            for (int r = 0; r < 4; ++r) {
                float v = acc[t][r] + bv + (float)res[(size_t)(growbase + r) * ncols + col];
                vals[t][r] = v;
                ss[r] += v * v;
            }
        }
#pragma unroll
        for (int r = 0; r < 4; ++r) {
            float s = ss[r];
            s += __shfl_xor(s, 1);
            s += __shfl_xor(s, 2);
            s += __shfl_xor(s, 4);
            s += __shfl_xor(s, 8);
            ss[r] = rsqrtf(s * (1.f / 128.f) + EPS_RMS);
        }
#pragma unroll
        for (int t = 0; t < 8; ++t) {
            int col = colbase + t * 16 + m;
            float nw = (float)normw[col];
#pragma unroll
            for (int r = 0; r < 4; ++r) {
                float o = vals[t][r] * ss[r] * nw;
                if (EPI == 2) Cb[(size_t)(growbase + r) * ncols + col] = (bf16_t)o;
                else          Cf[(size_t)(growbase + r) * ncols + col] = o;
            }
        }
    }
}

// ---------------- attention coefficients a_s, a_d ----------------
// one wave per node; lane: h = lane>>4, d0 = (lane&15)*8

__global__ __launch_bounds__(256) void attn_coef(const bf16_t* __restrict__ xp,
                                                 const bf16_t* __restrict__ att_s,
                                                 const bf16_t* __restrict__ att_d,
                                                 float* __restrict__ a_s,
                                                 float* __restrict__ a_d) {
    int wave = (int)((blockIdx.x * blockDim.x + threadIdx.x) >> 6);
    if (wave >= N_NODES) return;
    int lane = threadIdx.x & 63;
    int h = lane >> 4;
    int d0 = (lane & 15) * 8;
    bf16v8 xv = *reinterpret_cast<const bf16v8*>(xp + (size_t)wave * HD + h * DIM + d0);
    bf16v8 sv = *reinterpret_cast<const bf16v8*>(att_s + h * DIM + d0);
    bf16v8 dv = *reinterpret_cast<const bf16v8*>(att_d + h * DIM + d0);
    float ps = 0.f, pd = 0.f;
#pragma unroll
    for (int j = 0; j < 8; ++j) {
        float xf = (float)xv[j];
        ps += xf * (float)sv[j];
        pd += xf * (float)dv[j];
    }
    ps += __shfl_xor(ps, 1); ps += __shfl_xor(ps, 2);
    ps += __shfl_xor(ps, 4); ps += __shfl_xor(ps, 8);
    pd += __shfl_xor(pd, 1); pd += __shfl_xor(pd, 2);
    pd += __shfl_xor(pd, 4); pd += __shfl_xor(pd, 8);
    if ((lane & 15) == 0) {
        a_s[wave * 4 + h] = ps;
        a_d[wave * 4 + h] = pd;
    }
}

// ---------------- GAT aggregate + head-mean + bias + residual + rmsnorm ----------------
// one wave per dst node

__device__ __forceinline__ float leaky(float e) { return e > 0.f ? e : SLOPE * e; }

__global__ __launch_bounds__(256) void gat_agg(const int* __restrict__ row_ptr,
                                               const int* __restrict__ csr_src,
                                               const float* __restrict__ a_s,
                                               const float* __restrict__ a_d,
                                               const bf16_t* __restrict__ xp,
                                               const bf16_t* __restrict__ xres,
                                               const bf16_t* __restrict__ bias,
                                               const bf16_t* __restrict__ normw,
                                               bf16_t* __restrict__ out) {
    int n = (int)((blockIdx.x * blockDim.x + threadIdx.x) >> 6);
    if (n >= N_NODES) return;
    int lane = threadIdx.x & 63;
    int beg = row_ptr[n];
    int deg = row_ptr[n + 1] - beg;
    if (deg < 0) deg = 0;
    if (deg > NEDGE) deg = NEDGE;
    if (beg < 0) beg = 0;
    if (beg > NEDGE - deg) beg = NEDGE - deg;
    const float4 adv = reinterpret_cast<const float4*>(a_d)[n];

    // pass 1: per-head max (edges + self loop at i==deg)
    float m0 = -1e30f, m1 = -1e30f, m2 = -1e30f, m3 = -1e30f;
    for (int i = lane; i <= deg; i += 64) {
        int s = (i < deg) ? clamp_node(csr_src[beg + i]) : n;
        float4 av = reinterpret_cast<const float4*>(a_s)[s];
        m0 = fmaxf(m0, leaky(av.x + adv.x));
        m1 = fmaxf(m1, leaky(av.y + adv.y));
        m2 = fmaxf(m2, leaky(av.z + adv.z));
        m3 = fmaxf(m3, leaky(av.w + adv.w));
    }
#pragma unroll
    for (int msk = 1; msk < 64; msk <<= 1) {
        m0 = fmaxf(m0, __shfl_xor(m0, msk));
        m1 = fmaxf(m1, __shfl_xor(m1, msk));
        m2 = fmaxf(m2, __shfl_xor(m2, msk));
        m3 = fmaxf(m3, __shfl_xor(m3, msk));
    }
    // pass 2: denominators
    float s0 = 0.f, s1 = 0.f, s2 = 0.f, s3 = 0.f;
    for (int i = lane; i <= deg; i += 64) {
        int s = (i < deg) ? clamp_node(csr_src[beg + i]) : n;
        float4 av = reinterpret_cast<const float4*>(a_s)[s];
        s0 += __expf(leaky(av.x + adv.x) - m0);
        s1 += __expf(leaky(av.y + adv.y) - m1);
        s2 += __expf(leaky(av.z + adv.z) - m2);
        s3 += __expf(leaky(av.w + adv.w) - m3);
    }
#pragma unroll
    for (int msk = 1; msk < 64; msk <<= 1) {
        s0 += __shfl_xor(s0, msk);
        s1 += __shfl_xor(s1, msk);
        s2 += __shfl_xor(s2, msk);
        s3 += __shfl_xor(s3, msk);
    }
    int h = lane >> 4;
    int d0 = (lane & 15) * 8;
    float mh = h == 0 ? m0 : h == 1 ? m1 : h == 2 ? m2 : m3;
    float dh = h == 0 ? adv.x : h == 1 ? adv.y : h == 2 ? adv.z : adv.w;
    float ih = 1.f / (h == 0 ? s0 : h == 1 ? s1 : h == 2 ? s2 : s3);

    // pass 3: weighted aggregate; lanes cooperatively cover the 512-wide xp row
    float acc[8] = {0.f, 0.f, 0.f, 0.f, 0.f, 0.f, 0.f, 0.f};
    for (int e = 0; e <= deg; ++e) {
        int s = (e < deg) ? clamp_node(csr_src[beg + e]) : n;
        float ev = leaky(a_s[s * 4 + h] + dh);
        float w = __expf(ev - mh) * ih;
        bf16v8 xv = *reinterpret_cast<const bf16v8*>(xp + (size_t)s * HD + h * DIM + d0);
#pragma unroll
        for (int j = 0; j < 8; ++j) acc[j] += w * (float)xv[j];
    }
    // head mean across the 4 groups of 16 lanes
#pragma unroll
    for (int j = 0; j < 8; ++j) {
        acc[j] += __shfl_xor(acc[j], 16);
        acc[j] += __shfl_xor(acc[j], 32);
        acc[j] *= 0.25f;
    }
    // + bias + residual, rmsnorm
    bf16v8 rv = *reinterpret_cast<const bf16v8*>(xres + (size_t)n * DIM + d0);
    bf16v8 bv = *reinterpret_cast<const bf16v8*>(bias + d0);
    float vals[8];
    float ss = 0.f;
#pragma unroll
    for (int j = 0; j < 8; ++j) {
        float v = acc[j] + (float)bv[j] + (float)rv[j];
        vals[j] = v;
        ss += v * v;
    }
    ss += __shfl_xor(ss, 1); ss += __shfl_xor(ss, 2);
    ss += __shfl_xor(ss, 4); ss += __shfl_xor(ss, 8);
    float scale = rsqrtf(ss * (1.f / 128.f) + EPS_RMS);
    if (h == 0) {
        bf16v8 nw = *reinterpret_cast<const bf16v8*>(normw + d0);
        bf16v8 ov;
#pragma unroll
        for (int j = 0; j < 8; ++j) ov[j] = (bf16_t)(vals[j] * scale * (float)nw[j]);
        *reinterpret_cast<bf16v8*>(out + (size_t)n * DIM + d0) = ov;
    }
}

// ---------------- launch ----------------

extern "C" void kernel_launch(void* const* d_in, const int* in_sizes, int n_in,
                              void* d_out, int out_size, void* d_ws, size_t ws_size,
                              hipStream_t stream) {
    const void* x_in   = d_in[0];
    const void* W_gat  = d_in[1];
    const void* att_s  = d_in[2];
    const void* att_d  = d_in[3];
    const void* bias_g = d_in[4];
    const void* W1     = d_in[5];
    const void* b1     = d_in[6];
    const void* W2     = d_in[7];
    const void* b2     = d_in[8];
    const void* n1w    = d_in[9];
    const void* n2w    = d_in[10];
    const int*  ei     = (const int*)d_in[11];

    char* ws = (char*)d_ws;
    size_t off = 0;
    auto alloc = [&](size_t bytes) {
        void* p = ws + off;
        off = (off + bytes + 255) & ~(size_t)255;
        return p;
    };
    // total ~33.5 MB (hbuf aliases xp; xb doubles as the recurrent x buffer)
    bf16_t* WgT     = (bf16_t*)alloc((size_t)LAYERS * HD * DIM * 2);
    bf16_t* W1T     = (bf16_t*)alloc((size_t)LAYERS * DIM * DIM * 2);
    bf16_t* W2T     = (bf16_t*)alloc((size_t)LAYERS * DIM * DIM * 2);
    bf16_t* xb      = (bf16_t*)alloc((size_t)N_NODES * DIM * 2);   // canonical bf16 x chain
    bf16_t* xp      = (bf16_t*)alloc((size_t)N_NODES * HD * 2);
    bf16_t* hbuf    = xp;  // alias: xp dead before hbuf written; rewritten next layer
    float*  a_s     = (float*)alloc((size_t)N_NODES * NH * 4);
    float*  a_d     = (float*)alloc((size_t)N_NODES * NH * 4);
    int*    eflag   = (int*)alloc(4);
    int*    fflag   = (int*)alloc(4);
    int*    deg     = (int*)alloc((size_t)N_NODES * 4);
    int*    cursor  = (int*)alloc((size_t)N_NODES * 4);
    int*    row_ptr = (int*)alloc((size_t)(N_NODES + 1) * 4);
    int*    csr     = (int*)alloc((size_t)NEDGE * 4);
    bf16_t* xmid    = (bf16_t*)alloc((size_t)N_NODES * DIM * 2);
    bf16_t* attSc   = (bf16_t*)alloc((size_t)LAYERS * NH * DIM * 2);
    bf16_t* attDc   = (bf16_t*)alloc((size_t)LAYERS * NH * DIM * 2);
    bf16_t* bgc     = (bf16_t*)alloc((size_t)LAYERS * DIM * 2);
    bf16_t* b1c     = (bf16_t*)alloc((size_t)LAYERS * DIM * 2);
    bf16_t* b2c     = (bf16_t*)alloc((size_t)LAYERS * DIM * 2);
    bf16_t* n1c     = (bf16_t*)alloc((size_t)LAYERS * DIM * 2);
    bf16_t* n2c     = (bf16_t*)alloc((size_t)LAYERS * DIM * 2);

    // --- dtype detection ---
    hipMemsetAsync(eflag, 0, 4, stream);
    hipMemsetAsync(deg, 0, (size_t)N_NODES * 4, stream);
    detect_f32_kernel<<<1, 1024, 0, stream>>>((const unsigned short*)x_in, fflag);
    detect_int64_kernel<<<1, 1024, 0, stream>>>(ei, eflag);

    // --- canonicalize inputs to bf16 ---
    convert_kernel<<<(N_NODES * DIM + 255) / 256, 256, 0, stream>>>(x_in, xb, N_NODES * DIM, fflag);
    transpose_convert_kernel<<<(LAYERS * DIM * HD + 255) / 256, 256, 0, stream>>>(W_gat, WgT, DIM, HD, LAYERS, fflag);
    transpose_convert_kernel<<<(LAYERS * DIM * DIM + 255) / 256, 256, 0, stream>>>(W1, W1T, DIM, DIM, LAYERS, fflag);
    transpose_convert_kernel<<<(LAYERS * DIM * DIM + 255) / 256, 256, 0, stream>>>(W2, W2T, DIM, DIM, LAYERS, fflag);
    convert_kernel<<<(LAYERS * NH * DIM + 255) / 256, 256, 0, stream>>>(att_s, attSc, LAYERS * NH * DIM, fflag);
    convert_kernel<<<(LAYERS * NH * DIM + 255) / 256, 256, 0, stream>>>(att_d, attDc, LAYERS * NH * DIM, fflag);
    convert_kernel<<<(LAYERS * DIM + 255) / 256, 256, 0, stream>>>(bias_g, bgc, LAYERS * DIM, fflag);
    convert_kernel<<<(LAYERS * DIM + 255) / 256, 256, 0, stream>>>(b1, b1c, LAYERS * DIM, fflag);
    convert_kernel<<<(LAYERS * DIM + 255) / 256, 256, 0, stream>>>(b2, b2c, LAYERS * DIM, fflag);
    convert_kernel<<<(LAYERS * DIM + 255) / 256, 256, 0, stream>>>(n1w, n1c, LAYERS * DIM, fflag);
    convert_kernel<<<(LAYERS * DIM + 255) / 256, 256, 0, stream>>>(n2w, n2c, LAYERS * DIM, fflag);

    // --- CSR build ---
    hist_kernel<<<(NEDGE + 255) / 256, 256, 0, stream>>>(ei, deg, eflag);
    scan_kernel<<<1, 1024, 0, stream>>>(deg, row_ptr, cursor);
    fill_kernel<<<(NEDGE + 255) / 256, 256, 0, stream>>>(ei, cursor, csr, eflag);

    for (int l = 0; l < LAYERS; ++l) {
        // xp = x @ Wg   (20000x128 @ 128x512)
        gemm16<0><<<1250, 256, 0, stream>>>(xb, WgT + (size_t)l * HD * DIM,
                                            nullptr, nullptr, nullptr, xp, N_NODES, HD);
        attn_coef<<<5000, 256, 0, stream>>>(xp, attSc + (size_t)l * NH * DIM,
                                            attDc + (size_t)l * NH * DIM, a_s, a_d);
        gat_agg<<<5000, 256, 0, stream>>>(row_ptr, csr, a_s, a_d, xp, xb,
                                          bgc + (size_t)l * DIM, n1c + (size_t)l * DIM, xmid);
        // h = relu(xmid @ W1 + b1)
        gemm16<1><<<313, 256, 0, stream>>>(xmid, W1T + (size_t)l * DIM * DIM,
                                           b1c + (size_t)l * DIM, nullptr, nullptr, hbuf, N_NODES, DIM);
        // x = rmsnorm(xmid + h @ W2 + b2):
        //   layers 0,1 -> bf16 into xb (next layer's input; xb fully consumed above)
        //   layer  2   -> f32 into d_out (reference output dtype is float32)
        if (l < LAYERS - 1) {
            gemm16<2><<<313, 256, 0, stream>>>(hbuf, W2T + (size_t)l * DIM * DIM,
                                               b2c + (size_t)l * DIM, xmid, n2c + (size_t)l * DIM,
                                               xb, N_NODES, DIM);
        } else {
            gemm16<3><<<313, 256, 0, stream>>>(hbuf, W2T + (size_t)l * DIM * DIM,
                                               b2c + (size_t)l * DIM, xmid, n2c + (size_t)l * DIM,
                                               d_out, N_NODES, DIM);
        }
    }
}

// Round 5
// 475.221 us; speedup vs baseline: 1.1121x; 1.1121x over previous
//
#include <hip/hip_runtime.h>
#include <hip/hip_bf16.h>

#define N_NODES 20000
#define NEDGE   320000
#define DIM     128
#define NH      4
#define HD      512   // NH*DIM
#define LAYERS  3
#define EPS_RMS 1.1920929e-07f
#define SLOPE   0.2f
#define DEGCAP  128   // LDS-staged softmax weights per node (Poisson(16) tail << 128)

typedef __bf16 bf16_t;
typedef __bf16 bf16v8 __attribute__((ext_vector_type(8)));
typedef float  f32v4  __attribute__((ext_vector_type(4)));

__device__ __forceinline__ int clamp_node(int s) {
    return ((unsigned)s >= (unsigned)N_NODES) ? 0 : s;
}
__device__ __forceinline__ float leaky(float e) { return e > 0.f ? e : SLOPE * e; }
__device__ __forceinline__ float selc(float4 v, int h) {
    return h == 0 ? v.x : h == 1 ? v.y : h == 2 ? v.z : v.w;
}

// ---------------- dtype detection ----------------
__global__ void detect_f32_kernel(const unsigned short* __restrict__ x,
                                  int* __restrict__ isbf16) {
    __shared__ int cnt;
    if (threadIdx.x == 0) cnt = 0;
    __syncthreads();
    unsigned short h = x[2 * threadIdx.x];
    int e = (h >> 7) & 0xff;
    if (e >= 96 && e <= 140) atomicAdd(&cnt, 1);
    __syncthreads();
    if (threadIdx.x == 0) *isbf16 = (cnt >= 700) ? 1 : 0;
}

__global__ void detect_int64_kernel(const int* __restrict__ ei, int* __restrict__ flag) {
    int t = threadIdx.x;
    if (ei[2 * t + 1] != 0) atomicAdd(flag, 1);
}

__device__ __forceinline__ int edge_src(const int* ei, int e, bool is64) {
    return clamp_node(is64 ? ei[2 * e] : ei[e]);
}
__device__ __forceinline__ int edge_dst(const int* ei, int e, bool is64) {
    return clamp_node(is64 ? ei[2 * NEDGE + 2 * e] : ei[NEDGE + e]);
}

// ---------------- input canonicalization (f32|bf16 -> bf16) ----------------

__device__ __forceinline__ bf16_t cvt_elem(const void* in, size_t j, bool isbf) {
    return isbf ? ((const bf16_t*)in)[j] : (bf16_t)((const float*)in)[j];
}

__global__ void convert_kernel(const void* __restrict__ in, bf16_t* __restrict__ out,
                               int n, const int* __restrict__ isbf16) {
    int i = blockIdx.x * blockDim.x + threadIdx.x;
    if (i >= n) return;
    out[i] = cvt_elem(in, i, *isbf16 != 0);
}

// all 7 small parameter arrays in one launch
__global__ void convert_small(const void* aS, const void* aD, const void* bg,
                              const void* b1, const void* b2, const void* n1, const void* n2,
                              bf16_t* aSc, bf16_t* aDc, bf16_t* bgc, bf16_t* b1c,
                              bf16_t* b2c, bf16_t* n1c, bf16_t* n2c,
                              const int* __restrict__ isbf16) {
    const int A = LAYERS * NH * DIM;   // 1536
    const int V = LAYERS * DIM;        // 384
    int i = blockIdx.x * blockDim.x + threadIdx.x;
    bool b = (*isbf16 != 0);
    if (i < A) { aSc[i] = cvt_elem(aS, i, b); return; }
    i -= A;
    if (i < A) { aDc[i] = cvt_elem(aD, i, b); return; }
    i -= A;
    if (i >= 5 * V) return;
    int seg = i / V, k = i - seg * V;
    if (seg == 0) bgc[k] = cvt_elem(bg, k, b);
    else if (seg == 1) b1c[k] = cvt_elem(b1, k, b);
    else if (seg == 2) b2c[k] = cvt_elem(b2, k, b);
    else if (seg == 3) n1c[k] = cvt_elem(n1, k, b);
    else n2c[k] = cvt_elem(n2, k, b);
}

// out[l][c][k] = in[l][k][c], with dtype conversion
__global__ void transpose_convert_kernel(const void* __restrict__ in, bf16_t* __restrict__ out,
                                         int K, int C, int L, const int* __restrict__ isbf16) {
    int idx = blockIdx.x * blockDim.x + threadIdx.x;
    int total = K * C * L;
    if (idx >= total) return;
    int l = idx / (K * C);
    int rem = idx - l * (K * C);
    int c = rem / K;
    int k = rem - c * K;
    out[idx] = cvt_elem(in, (size_t)l * K * C + (size_t)k * C + c, *isbf16 != 0);
}

// ---------------- CSR build ----------------

__global__ void hist_kernel(const int* __restrict__ ei, int* __restrict__ deg,
                            const int* __restrict__ flag) {
    int e = blockIdx.x * blockDim.x + threadIdx.x;
    bool is64 = (*flag == 0);
    if (e < NEDGE) atomicAdd(&deg[edge_dst(ei, e, is64)], 1);
}

// shuffle-based scan: 2 barriers per 1024-chunk instead of 10
__global__ __launch_bounds__(1024) void scan_kernel(const int* __restrict__ deg,
                                                    int* __restrict__ row_ptr,
                                                    int* __restrict__ cursor) {
    __shared__ int wsum[16];
    __shared__ int carry_s;
    int tid = threadIdx.x, lane = tid & 63, wv = tid >> 6;
    if (tid == 0) { carry_s = 0; row_ptr[0] = 0; }
    __syncthreads();
    for (int base = 0; base < N_NODES; base += 1024) {
        int idx = base + tid;
        int v = (idx < N_NODES) ? deg[idx] : 0;
        int x = v;
#pragma unroll
        for (int off = 1; off < 64; off <<= 1) {
            int t = __shfl_up(x, off);
            if (lane >= off) x += t;
        }
        if (lane == 63) wsum[wv] = x;
        __syncthreads();
        if (wv == 0) {
            int s = (lane < 16) ? wsum[lane] : 0;
#pragma unroll
            for (int off = 1; off < 16; off <<= 1) {
                int t = __shfl_up(s, off);
                if (lane >= off) s += t;
            }
            if (lane < 16) wsum[lane] = s;
        }
        __syncthreads();
        int woff = (wv == 0) ? 0 : wsum[wv - 1];
        int c = carry_s;
        int incl = x + woff + c;
        if (idx < N_NODES) {
            row_ptr[idx + 1] = incl;
            cursor[idx] = incl - v;
        }
        __syncthreads();
        if (tid == 1023) carry_s = incl;
        __syncthreads();
    }
}

__global__ void fill_kernel(const int* __restrict__ ei, int* __restrict__ cursor,
                            int* __restrict__ csr_src, const int* __restrict__ flag) {
    int e = blockIdx.x * blockDim.x + threadIdx.x;
    bool is64 = (*flag == 0);
    if (e < NEDGE) {
        int d = edge_dst(ei, e, is64);
        int pos = atomicAdd(&cursor[d], 1);
        if ((unsigned)pos < (unsigned)NEDGE) csr_src[pos] = edge_src(ei, e, is64);
    }
}

// ---------------- GEMM (one wave = 16 rows x 128 cols, K=128) ----------------
// EPI 0: store C (bf16) + fused a_s/a_d dot products (xp = x @ Wg, ncols=512)
// EPI 1: store relu(C+b) (bf16)
// EPI 2: store rmsnorm(res+C+b) bf16 (ncols=128)
// EPI 3: store rmsnorm(res+C+b) f32  (final layer -> d_out)

template <int EPI>
__global__ __launch_bounds__(256) void gemm16(const bf16_t* __restrict__ A,
                                              const bf16_t* __restrict__ Bt,
                                              const bf16_t* __restrict__ bias,
                                              const bf16_t* __restrict__ res,
                                              const bf16_t* __restrict__ normw,
                                              const bf16_t* __restrict__ attS,
                                              const bf16_t* __restrict__ attD,
                                              float* __restrict__ aSg,
                                              float* __restrict__ aDg,
                                              void* __restrict__ Cout,
                                              int M, int ncols) {
    int unitsPerRow = ncols >> 7;
    int unit = (int)((blockIdx.x * blockDim.x + threadIdx.x) >> 6);
    int totalUnits = (M >> 4) * unitsPerRow;
    if (unit >= totalUnits) return;
    int lane = threadIdx.x & 63;
    int row16 = unit / unitsPerRow;
    int colbase = (unit - row16 * unitsPerRow) << 7;
    int m = lane & 15;
    int kq = lane >> 4;

    const bf16_t* Arow = A + (size_t)(row16 * 16 + m) * DIM + kq * 8;
    bf16v8 a[4];
#pragma unroll
    for (int ks = 0; ks < 4; ++ks)
        a[ks] = *reinterpret_cast<const bf16v8*>(Arow + ks * 32);

    f32v4 acc[8];
#pragma unroll
    for (int t = 0; t < 8; ++t) acc[t] = (f32v4){0.f, 0.f, 0.f, 0.f};

    const bf16_t* Bbase = Bt + (size_t)(colbase + m) * DIM + kq * 8;
#pragma unroll
    for (int ks = 0; ks < 4; ++ks) {
#pragma unroll
        for (int t = 0; t < 8; ++t) {
            bf16v8 b = *reinterpret_cast<const bf16v8*>(Bbase + (size_t)t * 16 * DIM + ks * 32);
            acc[t] = __builtin_amdgcn_mfma_f32_16x16x32_bf16(a[ks], b, acc[t], 0, 0, 0);
        }
    }

    int growbase = row16 * 16 + kq * 4;
    bf16_t* Cb = (bf16_t*)Cout;
    float*  Cf = (float*)Cout;
    if (EPI == 0) {
        // fused attention coefficients: this wave's 128-col block == head hh,
        // d = t*16+m covers all 128 dims -> full per-row dot, no atomics
        int hh = colbase >> 7;
        float as8[8], ad8[8];
#pragma unroll
        for (int t = 0; t < 8; ++t) {
            as8[t] = (float)attS[hh * DIM + t * 16 + m];
            ad8[t] = (float)attD[hh * DIM + t * 16 + m];
        }
#pragma unroll
        for (int r = 0; r < 4; ++r) {
            float ps = 0.f, pd = 0.f;
#pragma unroll
            for (int t = 0; t < 8; ++t) {
                ps += acc[t][r] * as8[t];
                pd += acc[t][r] * ad8[t];
            }
            ps += __shfl_xor(ps, 1); ps += __shfl_xor(ps, 2);
            ps += __shfl_xor(ps, 4); ps += __shfl_xor(ps, 8);
            pd += __shfl_xor(pd, 1); pd += __shfl_xor(pd, 2);
            pd += __shfl_xor(pd, 4); pd += __shfl_xor(pd, 8);
            if (m == 0) {
                int row = growbase + r;
                aSg[row * 4 + hh] = ps;
                aDg[row * 4 + hh] = pd;
            }
        }
#pragma unroll
        for (int t = 0; t < 8; ++t) {
            int col = colbase + t * 16 + m;
#pragma unroll
            for (int r = 0; r < 4; ++r)
                Cb[(size_t)(growbase + r) * ncols + col] = (bf16_t)acc[t][r];
        }
    } else if (EPI == 1) {
#pragma unroll
        for (int t = 0; t < 8; ++t) {
            int col = colbase + t * 16 + m;
            float bv = (float)bias[col];
#pragma unroll
            for (int r = 0; r < 4; ++r) {
                float v = acc[t][r] + bv;
                v = v > 0.f ? v : 0.f;
                Cb[(size_t)(growbase + r) * ncols + col] = (bf16_t)v;
            }
        }
    } else {
        float vals[8][4];
        float ss[4] = {0.f, 0.f, 0.f, 0.f};
#pragma unroll
        for (int t = 0; t < 8; ++t) {
            int col = colbase + t * 16 + m;
            float bv = (float)bias[col];
#pragma unroll
            for (int r = 0; r < 4; ++r) {
                float v = acc[t][r] + bv + (float)res[(size_t)(growbase + r) * ncols + col];
                vals[t][r] = v;
                ss[r] += v * v;
            }
        }
#pragma unroll
        for (int r = 0; r < 4; ++r) {
            float s = ss[r];
            s += __shfl_xor(s, 1);
            s += __shfl_xor(s, 2);
            s += __shfl_xor(s, 4);
            s += __shfl_xor(s, 8);
            ss[r] = rsqrtf(s * (1.f / 128.f) + EPS_RMS);
        }
#pragma unroll
        for (int t = 0; t < 8; ++t) {
            int col = colbase + t * 16 + m;
            float nw = (float)normw[col];
#pragma unroll
            for (int r = 0; r < 4; ++r) {
                float o = vals[t][r] * ss[r] * nw;
                if (EPI == 2) Cb[(size_t)(growbase + r) * ncols + col] = (bf16_t)o;
                else          Cf[(size_t)(growbase + r) * ncols + col] = o;
            }
        }
    }
}

// ---------------- GAT aggregate + head-mean + bias + residual + rmsnorm ----------------
// one wave per dst node. LDS stages softmax weights (wave-private, no barriers);
// pass 3 unrolled x4 with independent gathers to hide latency.

__global__ __launch_bounds__(256) void gat_agg(const int* __restrict__ row_ptr,
                                               const int* __restrict__ csr_src,
                                               const float* __restrict__ a_s,
                                               const float* __restrict__ a_d,
                                               const bf16_t* __restrict__ xp,
                                               const bf16_t* __restrict__ xres,
                                               const bf16_t* __restrict__ bias,
                                               const bf16_t* __restrict__ normw,
                                               bf16_t* __restrict__ out) {
    __shared__ float4 wlds[4][DEGCAP];   // 8 KB, wave-private slices
    int n = (int)((blockIdx.x * blockDim.x + threadIdx.x) >> 6);
    if (n >= N_NODES) return;
    int lane = threadIdx.x & 63;
    int wv = (threadIdx.x >> 6);
    int beg = row_ptr[n];
    int deg = row_ptr[n + 1] - beg;
    if (deg < 0) deg = 0;
    if (deg > NEDGE) deg = NEDGE;
    if (beg < 0) beg = 0;
    if (beg > NEDGE - deg) beg = NEDGE - deg;

    const float4* a_s4 = reinterpret_cast<const float4*>(a_s);
    const float4 adv = reinterpret_cast<const float4*>(a_d)[n];
    const float4 avs = a_s4[n];
    int h = lane >> 4;
    int d0 = (lane & 15) * 8;
    // early issue: self row + my edge index
    bf16v8 xvself = *reinterpret_cast<const bf16v8*>(xp + (size_t)n * HD + h * DIM + d0);
    int s_reg = (lane < deg) ? clamp_node(csr_src[beg + lane]) : n;

    float4 ev_self = {leaky(avs.x + adv.x), leaky(avs.y + adv.y),
                      leaky(avs.z + adv.z), leaky(avs.w + adv.w)};

    // pass 1: e-values -> LDS, running max (self included)
    float4 m4 = ev_self;
    for (int i = lane; i < deg; i += 64) {
        int s = (i == lane) ? s_reg : clamp_node(csr_src[beg + i]);
        float4 av = a_s4[s];
        float4 ev = {leaky(av.x + adv.x), leaky(av.y + adv.y),
                     leaky(av.z + adv.z), leaky(av.w + adv.w)};
        if (i < DEGCAP) wlds[wv][i] = ev;
        m4.x = fmaxf(m4.x, ev.x); m4.y = fmaxf(m4.y, ev.y);
        m4.z = fmaxf(m4.z, ev.z); m4.w = fmaxf(m4.w, ev.w);
    }
#pragma unroll
    for (int msk = 1; msk < 64; msk <<= 1) {
        m4.x = fmaxf(m4.x, __shfl_xor(m4.x, msk));
        m4.y = fmaxf(m4.y, __shfl_xor(m4.y, msk));
        m4.z = fmaxf(m4.z, __shfl_xor(m4.z, msk));
        m4.w = fmaxf(m4.w, __shfl_xor(m4.w, msk));
    }
    // pass 2: exp -> LDS, running sum
    float4 s4 = {0.f, 0.f, 0.f, 0.f};
    for (int i = lane; i < deg; i += 64) {
        float4 ev;
        if (i < DEGCAP) ev = wlds[wv][i];
        else {
            int s = clamp_node(csr_src[beg + i]);
            float4 av = a_s4[s];
            ev = {leaky(av.x + adv.x), leaky(av.y + adv.y),
                  leaky(av.z + adv.z), leaky(av.w + adv.w)};
        }
        float4 ex = {__expf(ev.x - m4.x), __expf(ev.y - m4.y),
                     __expf(ev.z - m4.z), __expf(ev.w - m4.w)};
        if (i < DEGCAP) wlds[wv][i] = ex;
        s4.x += ex.x; s4.y += ex.y; s4.z += ex.z; s4.w += ex.w;
    }
#pragma unroll
    for (int msk = 1; msk < 64; msk <<= 1) {
        s4.x += __shfl_xor(s4.x, msk);
        s4.y += __shfl_xor(s4.y, msk);
        s4.z += __shfl_xor(s4.z, msk);
        s4.w += __shfl_xor(s4.w, msk);
    }
    // self exp, added uniformly after reduction
    float4 exs = {__expf(ev_self.x - m4.x), __expf(ev_self.y - m4.y),
                  __expf(ev_self.z - m4.z), __expf(ev_self.w - m4.w)};
    s4.x += exs.x; s4.y += exs.y; s4.z += exs.z; s4.w += exs.w;

    float mh = selc(m4, h);
    float dh = selc(adv, h);
    float ih = 1.f / selc(s4, h);
    float wself = selc(exs, h);

    // pass 3: weighted aggregate, 4 independent gathers in flight
    float accv[8];
#pragma unroll
    for (int j = 0; j < 8; ++j) accv[j] = wself * (float)xvself[j];

    const float* wrow = (const float*)&wlds[wv][0];
    for (int b0 = 0; b0 < deg; b0 += 4) {
        int cnt = deg - b0; if (cnt > 4) cnt = 4;
        bf16v8 xv[4]; float wv4[4];
#pragma unroll
        for (int u = 0; u < 4; ++u) {
            if (u < cnt) {
                int e = b0 + u;
                int s = (e < 64) ? __shfl(s_reg, e) : clamp_node(csr_src[beg + e]);
                xv[u] = *reinterpret_cast<const bf16v8*>(xp + (size_t)s * HD + h * DIM + d0);
                if (e < DEGCAP) wv4[u] = wrow[e * 4 + h];
                else {
                    float as = a_s[s * 4 + h];
                    wv4[u] = __expf(leaky(as + dh) - mh);
                }
            }
        }
#pragma unroll
        for (int u = 0; u < 4; ++u) {
            if (u < cnt) {
#pragma unroll
                for (int j = 0; j < 8; ++j) accv[j] += wv4[u] * (float)xv[u][j];
            }
        }
    }
#pragma unroll
    for (int j = 0; j < 8; ++j) accv[j] *= ih;

    // head mean across the 4 groups of 16 lanes
#pragma unroll
    for (int j = 0; j < 8; ++j) {
        accv[j] += __shfl_xor(accv[j], 16);
        accv[j] += __shfl_xor(accv[j], 32);
        accv[j] *= 0.25f;
    }
    // + bias + residual, rmsnorm
    bf16v8 rv = *reinterpret_cast<const bf16v8*>(xres + (size_t)n * DIM + d0);
    bf16v8 bv = *reinterpret_cast<const bf16v8*>(bias + d0);
    float vals[8];
    float ss = 0.f;
#pragma unroll
    for (int j = 0; j < 8; ++j) {
        float v = accv[j] + (float)bv[j] + (float)rv[j];
        vals[j] = v;
        ss += v * v;
    }
    ss += __shfl_xor(ss, 1); ss += __shfl_xor(ss, 2);
    ss += __shfl_xor(ss, 4); ss += __shfl_xor(ss, 8);
    float scale = rsqrtf(ss * (1.f / 128.f) + EPS_RMS);
    if (h == 0) {
        bf16v8 nw = *reinterpret_cast<const bf16v8*>(normw + d0);
        bf16v8 ov;
#pragma unroll
        for (int j = 0; j < 8; ++j) ov[j] = (bf16_t)(vals[j] * scale * (float)nw[j]);
        *reinterpret_cast<bf16v8*>(out + (size_t)n * DIM + d0) = ov;
    }
}

// ---------------- launch ----------------

extern "C" void kernel_launch(void* const* d_in, const int* in_sizes, int n_in,
                              void* d_out, int out_size, void* d_ws, size_t ws_size,
                              hipStream_t stream) {
    const void* x_in   = d_in[0];
    const void* W_gat  = d_in[1];
    const void* att_s  = d_in[2];
    const void* att_d  = d_in[3];
    const void* bias_g = d_in[4];
    const void* W1     = d_in[5];
    const void* b1     = d_in[6];
    const void* W2     = d_in[7];
    const void* b2     = d_in[8];
    const void* n1w    = d_in[9];
    const void* n2w    = d_in[10];
    const int*  ei     = (const int*)d_in[11];

    char* ws = (char*)d_ws;
    size_t off = 0;
    auto alloc = [&](size_t bytes) {
        void* p = ws + off;
        off = (off + bytes + 255) & ~(size_t)255;
        return p;
    };
    bf16_t* WgT     = (bf16_t*)alloc((size_t)LAYERS * HD * DIM * 2);
    bf16_t* W1T     = (bf16_t*)alloc((size_t)LAYERS * DIM * DIM * 2);
    bf16_t* W2T     = (bf16_t*)alloc((size_t)LAYERS * DIM * DIM * 2);
    bf16_t* xb      = (bf16_t*)alloc((size_t)N_NODES * DIM * 2);
    bf16_t* xp      = (bf16_t*)alloc((size_t)N_NODES * HD * 2);
    bf16_t* hbuf    = xp;  // alias: xp dead before hbuf written; rewritten next layer
    float*  a_s     = (float*)alloc((size_t)N_NODES * NH * 4);
    float*  a_d     = (float*)alloc((size_t)N_NODES * NH * 4);
    int*    eflag   = (int*)alloc(4);
    int*    fflag   = (int*)alloc(4);
    int*    deg     = (int*)alloc((size_t)N_NODES * 4);
    int*    cursor  = (int*)alloc((size_t)N_NODES * 4);
    int*    row_ptr = (int*)alloc((size_t)(N_NODES + 1) * 4);
    int*    csr     = (int*)alloc((size_t)NEDGE * 4);
    bf16_t* xmid    = (bf16_t*)alloc((size_t)N_NODES * DIM * 2);
    bf16_t* attSc   = (bf16_t*)alloc((size_t)LAYERS * NH * DIM * 2);
    bf16_t* attDc   = (bf16_t*)alloc((size_t)LAYERS * NH * DIM * 2);
    bf16_t* bgc     = (bf16_t*)alloc((size_t)LAYERS * DIM * 2);
    bf16_t* b1c     = (bf16_t*)alloc((size_t)LAYERS * DIM * 2);
    bf16_t* b2c     = (bf16_t*)alloc((size_t)LAYERS * DIM * 2);
    bf16_t* n1c     = (bf16_t*)alloc((size_t)LAYERS * DIM * 2);
    bf16_t* n2c     = (bf16_t*)alloc((size_t)LAYERS * DIM * 2);

    // --- dtype detection ---
    hipMemsetAsync(eflag, 0, 4, stream);
    hipMemsetAsync(deg, 0, (size_t)N_NODES * 4, stream);
    detect_f32_kernel<<<1, 1024, 0, stream>>>((const unsigned short*)x_in, fflag);
    detect_int64_kernel<<<1, 1024, 0, stream>>>(ei, eflag);

    // --- canonicalize inputs to bf16 ---
    convert_kernel<<<(N_NODES * DIM + 255) / 256, 256, 0, stream>>>(x_in, xb, N_NODES * DIM, fflag);
    transpose_convert_kernel<<<(LAYERS * DIM * HD + 255) / 256, 256, 0, stream>>>(W_gat, WgT, DIM, HD, LAYERS, fflag);
    transpose_convert_kernel<<<(LAYERS * DIM * DIM + 255) / 256, 256, 0, stream>>>(W1, W1T, DIM, DIM, LAYERS, fflag);
    transpose_convert_kernel<<<(LAYERS * DIM * DIM + 255) / 256, 256, 0, stream>>>(W2, W2T, DIM, DIM, LAYERS, fflag);
    convert_small<<<(2 * LAYERS * NH * DIM + 5 * LAYERS * DIM + 255) / 256, 256, 0, stream>>>(
        att_s, att_d, bias_g, b1, b2, n1w, n2w,
        attSc, attDc, bgc, b1c, b2c, n1c, n2c, fflag);

    // --- CSR build ---
    hist_kernel<<<(NEDGE + 255) / 256, 256, 0, stream>>>(ei, deg, eflag);
    scan_kernel<<<1, 1024, 0, stream>>>(deg, row_ptr, cursor);
    fill_kernel<<<(NEDGE + 255) / 256, 256, 0, stream>>>(ei, cursor, csr, eflag);

    for (int l = 0; l < LAYERS; ++l) {
        // xp = x @ Wg (20000x128 @ 128x512), fused a_s/a_d epilogue
        gemm16<0><<<1250, 256, 0, stream>>>(xb, WgT + (size_t)l * HD * DIM,
                                            nullptr, nullptr, nullptr,
                                            attSc + (size_t)l * NH * DIM,
                                            attDc + (size_t)l * NH * DIM,
                                            a_s, a_d, xp, N_NODES, HD);
        gat_agg<<<5000, 256, 0, stream>>>(row_ptr, csr, a_s, a_d, xp, xb,
                                          bgc + (size_t)l * DIM, n1c + (size_t)l * DIM, xmid);
        // h = relu(xmid @ W1 + b1)
        gemm16<1><<<313, 256, 0, stream>>>(xmid, W1T + (size_t)l * DIM * DIM,
                                           b1c + (size_t)l * DIM, nullptr, nullptr,
                                           nullptr, nullptr, nullptr, nullptr, hbuf, N_NODES, DIM);
        // x = rmsnorm(xmid + h @ W2 + b2)
        if (l < LAYERS - 1) {
            gemm16<2><<<313, 256, 0, stream>>>(hbuf, W2T + (size_t)l * DIM * DIM,
                                               b2c + (size_t)l * DIM, xmid, n2c + (size_t)l * DIM,
                                               nullptr, nullptr, nullptr, nullptr, xb, N_NODES, DIM);
        } else {
            gemm16<3><<<313, 256, 0, stream>>>(hbuf, W2T + (size_t)l * DIM * DIM,
                                               b2c + (size_t)l * DIM, xmid, n2c + (size_t)l * DIM,
                                               nullptr, nullptr, nullptr, nullptr, d_out, N_NODES, DIM);
        }
    }
}

// Round 6
// 412.738 us; speedup vs baseline: 1.2805x; 1.1514x over previous
//
#include <hip/hip_runtime.h>
#include <hip/hip_bf16.h>

#define N_NODES 20000
#define NEDGE   320000
#define DIM     128
#define NH      4
#define HD      512   // NH*DIM
#define LAYERS  3
#define EPS_RMS 1.1920929e-07f
#define SLOPE   0.2f
#define DEGCAP  128
#define NTILES  (N_NODES >> 4)   // 1250

typedef __bf16 bf16_t;
typedef __bf16 bf16v8 __attribute__((ext_vector_type(8)));
typedef float  f32v4  __attribute__((ext_vector_type(4)));

__device__ __forceinline__ int clamp_node(int s) {
    return ((unsigned)s >= (unsigned)N_NODES) ? 0 : s;
}
__device__ __forceinline__ float leaky(float e) { return e > 0.f ? e : SLOPE * e; }
__device__ __forceinline__ float selc(float4 v, int h) {
    return h == 0 ? v.x : h == 1 ? v.y : h == 2 ? v.z : v.w;
}

// ---- per-wave dtype detection (no separate kernels, no flag dependencies) ----
// bf16 N(0,1): exponent of even halfwords in [96,140] ~always. f32: even
// halfwords are low mantissa bits (~18% hit). Ballot across the wave.
__device__ __forceinline__ bool wave_detect_bf16(const unsigned short* xh) {
    int lane = threadIdx.x & 63;
    unsigned short hw = xh[2 * lane];
    int e = (hw >> 7) & 0xff;
    unsigned long long b = __ballot(e >= 96 && e <= 140);
    return __popcll(b) >= 48;
}
// int64 little-endian: high words all zero; int32 node ids: ~never all zero.
__device__ __forceinline__ bool wave_detect_i64(const int* ei) {
    int lane = threadIdx.x & 63;
    unsigned long long b = __ballot(ei[2 * lane + 1] != 0);
    return b == 0ULL;
}
__device__ __forceinline__ bf16_t cvt_elem(const void* in, size_t j, bool isbf) {
    return isbf ? ((const bf16_t*)in)[j] : (bf16_t)((const float*)in)[j];
}
__device__ __forceinline__ int edge_src(const int* ei, int e, bool is64) {
    return clamp_node(is64 ? ei[2 * e] : ei[e]);
}
__device__ __forceinline__ int edge_dst(const int* ei, int e, bool is64) {
    return clamp_node(is64 ? ei[2 * NEDGE + 2 * e] : ei[NEDGE + e]);
}

// ---------------- one-shot canonicalization: x, 3 transposed weights, 7 smalls ----------------
__global__ __launch_bounds__(256) void convert_all(
        const void* x, const void* Wg, const void* W1, const void* W2,
        const void* aS, const void* aD, const void* bg, const void* b1,
        const void* b2, const void* n1, const void* n2,
        bf16_t* xb, bf16_t* WgT, bf16_t* W1T, bf16_t* W2T,
        bf16_t* aSc, bf16_t* aDc, bf16_t* bgc, bf16_t* b1c,
        bf16_t* b2c, bf16_t* n1c, bf16_t* n2c) {
    const int NX  = N_NODES * DIM;
    const int NWG = LAYERS * DIM * HD;
    const int NW1 = LAYERS * DIM * DIM;
    const int NSM = LAYERS * NH * DIM;
    const int NV  = LAYERS * DIM;
    bool isbf = wave_detect_bf16((const unsigned short*)x);
    int i = blockIdx.x * blockDim.x + threadIdx.x;
    if (i < NX) { xb[i] = cvt_elem(x, i, isbf); return; }
    i -= NX;
    if (i < NWG) {  // WgT[l][c][k] = Wg[l][k][c], K=DIM rows, C=HD cols
        int l = i / (DIM * HD);
        int rem = i - l * (DIM * HD);
        int c = rem / DIM, k = rem - c * DIM;
        WgT[i] = cvt_elem(Wg, (size_t)l * DIM * HD + (size_t)k * HD + c, isbf);
        return;
    }
    i -= NWG;
    if (i < NW1) {
        int l = i / (DIM * DIM);
        int rem = i - l * (DIM * DIM);
        int c = rem / DIM, k = rem - c * DIM;
        W1T[i] = cvt_elem(W1, (size_t)l * DIM * DIM + (size_t)k * DIM + c, isbf);
        return;
    }
    i -= NW1;
    if (i < NW1) {
        int l = i / (DIM * DIM);
        int rem = i - l * (DIM * DIM);
        int c = rem / DIM, k = rem - c * DIM;
        W2T[i] = cvt_elem(W2, (size_t)l * DIM * DIM + (size_t)k * DIM + c, isbf);
        return;
    }
    i -= NW1;
    if (i < NSM) { aSc[i] = cvt_elem(aS, i, isbf); return; }
    i -= NSM;
    if (i < NSM) { aDc[i] = cvt_elem(aD, i, isbf); return; }
    i -= NSM;
    if (i >= 5 * NV) return;
    int seg = i / NV, k = i - seg * NV;
    if (seg == 0) bgc[k] = cvt_elem(bg, k, isbf);
    else if (seg == 1) b1c[k] = cvt_elem(b1, k, isbf);
    else if (seg == 2) b2c[k] = cvt_elem(b2, k, isbf);
    else if (seg == 3) n1c[k] = cvt_elem(n1, k, isbf);
    else n2c[k] = cvt_elem(n2, k, isbf);
}

// ---------------- CSR build ----------------
__global__ void hist_kernel(const int* __restrict__ ei, int* __restrict__ deg) {
    bool is64 = wave_detect_i64(ei);
    int e = blockIdx.x * blockDim.x + threadIdx.x;
    if (e < NEDGE) atomicAdd(&deg[edge_dst(ei, e, is64)], 1);
}

__global__ __launch_bounds__(1024) void scan_kernel(const int* __restrict__ deg,
                                                    int* __restrict__ row_ptr,
                                                    int* __restrict__ cursor) {
    __shared__ int wsum[16];
    __shared__ int carry_s;
    int tid = threadIdx.x, lane = tid & 63, wv = tid >> 6;
    if (tid == 0) { carry_s = 0; row_ptr[0] = 0; }
    __syncthreads();
    for (int base = 0; base < N_NODES; base += 1024) {
        int idx = base + tid;
        int v = (idx < N_NODES) ? deg[idx] : 0;
        int x = v;
#pragma unroll
        for (int off = 1; off < 64; off <<= 1) {
            int t = __shfl_up(x, off);
            if (lane >= off) x += t;
        }
        if (lane == 63) wsum[wv] = x;
        __syncthreads();
        if (wv == 0) {
            int s = (lane < 16) ? wsum[lane] : 0;
#pragma unroll
            for (int off = 1; off < 16; off <<= 1) {
                int t = __shfl_up(s, off);
                if (lane >= off) s += t;
            }
            if (lane < 16) wsum[lane] = s;
        }
        __syncthreads();
        int woff = (wv == 0) ? 0 : wsum[wv - 1];
        int c = carry_s;
        int incl = x + woff + c;
        if (idx < N_NODES) {
            row_ptr[idx + 1] = incl;
            cursor[idx] = incl - v;
        }
        __syncthreads();
        if (tid == 1023) carry_s = incl;
        __syncthreads();
    }
}

__global__ void fill_kernel(const int* __restrict__ ei, int* __restrict__ cursor,
                            int* __restrict__ csr_src) {
    bool is64 = wave_detect_i64(ei);
    int e = blockIdx.x * blockDim.x + threadIdx.x;
    if (e < NEDGE) {
        int d = edge_dst(ei, e, is64);
        int pos = atomicAdd(&cursor[d], 1);
        if ((unsigned)pos < (unsigned)NEDGE) csr_src[pos] = edge_src(ei, e, is64);
    }
}

// ---------------- attention GEMM: xp = x @ Wg, fused a_s/a_d epilogue ----------------
// grid (313, 4): blockIdx.y = column unit (head); 4 waves of a block share one
// 128x128 B-tile staged in LDS (pad 132 halfwords -> <=2-way bank aliasing).
__global__ __launch_bounds__(256) void gemm_att(const bf16_t* __restrict__ A,
                                                const bf16_t* __restrict__ Bt,
                                                const bf16_t* __restrict__ attS,
                                                const bf16_t* __restrict__ attD,
                                                float* __restrict__ aSg,
                                                float* __restrict__ aDg,
                                                bf16_t* __restrict__ C) {
    __shared__ bf16_t bl[128 * 132];
    int wv = threadIdx.x >> 6;
    int lane = threadIdx.x & 63;
    int m = lane & 15, kq = lane >> 4;
    int colbase = blockIdx.y << 7;

    const bf16_t* Bsrc = Bt + (size_t)colbase * DIM;
#pragma unroll
    for (int it = 0; it < 8; ++it) {
        int chunk = it * 256 + threadIdx.x;   // 2048 chunks of 8 halfwords
        int c = chunk >> 4, ko = (chunk & 15) * 8;
        *reinterpret_cast<bf16v8*>(&bl[c * 132 + ko]) =
            *reinterpret_cast<const bf16v8*>(&Bsrc[c * DIM + ko]);
    }
    __syncthreads();

    int row16 = blockIdx.x * 4 + wv;
    if (row16 >= NTILES) return;

    const bf16_t* Arow = A + (size_t)(row16 * 16 + m) * DIM + kq * 8;
    bf16v8 a[4];
#pragma unroll
    for (int ks = 0; ks < 4; ++ks)
        a[ks] = *reinterpret_cast<const bf16v8*>(Arow + ks * 32);

    f32v4 acc[8];
#pragma unroll
    for (int t = 0; t < 8; ++t) acc[t] = (f32v4){0.f, 0.f, 0.f, 0.f};
#pragma unroll
    for (int ks = 0; ks < 4; ++ks) {
#pragma unroll
        for (int t = 0; t < 8; ++t) {
            bf16v8 b = *reinterpret_cast<const bf16v8*>(&bl[(t * 16 + m) * 132 + ks * 32 + kq * 8]);
            acc[t] = __builtin_amdgcn_mfma_f32_16x16x32_bf16(a[ks], b, acc[t], 0, 0, 0);
        }
    }

    int growbase = row16 * 16 + kq * 4;
    int hh = blockIdx.y;
    float as8[8], ad8[8];
#pragma unroll
    for (int t = 0; t < 8; ++t) {
        as8[t] = (float)attS[hh * DIM + t * 16 + m];
        ad8[t] = (float)attD[hh * DIM + t * 16 + m];
    }
#pragma unroll
    for (int r = 0; r < 4; ++r) {
        float ps = 0.f, pd = 0.f;
#pragma unroll
        for (int t = 0; t < 8; ++t) {
            ps += acc[t][r] * as8[t];
            pd += acc[t][r] * ad8[t];
        }
        ps += __shfl_xor(ps, 1); ps += __shfl_xor(ps, 2);
        ps += __shfl_xor(ps, 4); ps += __shfl_xor(ps, 8);
        pd += __shfl_xor(pd, 1); pd += __shfl_xor(pd, 2);
        pd += __shfl_xor(pd, 4); pd += __shfl_xor(pd, 8);
        if (m == 0) {
            int row = growbase + r;
            aSg[row * 4 + hh] = ps;
            aDg[row * 4 + hh] = pd;
        }
    }
#pragma unroll
    for (int t = 0; t < 8; ++t) {
        int col = colbase + t * 16 + m;
#pragma unroll
        for (int r = 0; r < 4; ++r)
            C[(size_t)(growbase + r) * HD + col] = (bf16_t)acc[t][r];
    }
}

// ---------------- GAT aggregate + head-mean + bias + residual + rmsnorm ----------------
__global__ __launch_bounds__(256) void gat_agg(const int* __restrict__ row_ptr,
                                               const int* __restrict__ csr_src,
                                               const float* __restrict__ a_s,
                                               const float* __restrict__ a_d,
                                               const bf16_t* __restrict__ xp,
                                               const bf16_t* __restrict__ xres,
                                               const bf16_t* __restrict__ bias,
                                               const bf16_t* __restrict__ normw,
                                               bf16_t* __restrict__ out) {
    __shared__ float4 wlds[4][DEGCAP];   // 8 KB, wave-private
    int n = (int)((blockIdx.x * blockDim.x + threadIdx.x) >> 6);
    if (n >= N_NODES) return;
    int lane = threadIdx.x & 63;
    int wv = threadIdx.x >> 6;
    int beg = row_ptr[n];
    int deg = row_ptr[n + 1] - beg;
    if (deg < 0) deg = 0;
    if (deg > NEDGE) deg = NEDGE;
    if (beg < 0) beg = 0;
    if (beg > NEDGE - deg) beg = NEDGE - deg;

    const float4* a_s4 = reinterpret_cast<const float4*>(a_s);
    const float4 adv = reinterpret_cast<const float4*>(a_d)[n];
    const float4 avs = a_s4[n];
    int h = lane >> 4;
    int d0 = (lane & 15) * 8;
    bf16v8 xvself = *reinterpret_cast<const bf16v8*>(xp + (size_t)n * HD + h * DIM + d0);
    int s_reg = (lane < deg) ? clamp_node(csr_src[beg + lane]) : n;

    float4 ev_self = {leaky(avs.x + adv.x), leaky(avs.y + adv.y),
                      leaky(avs.z + adv.z), leaky(avs.w + adv.w)};

    float4 m4 = ev_self;
    for (int i = lane; i < deg; i += 64) {
        int s = (i == lane) ? s_reg : clamp_node(csr_src[beg + i]);
        float4 av = a_s4[s];
        float4 ev = {leaky(av.x + adv.x), leaky(av.y + adv.y),
                     leaky(av.z + adv.z), leaky(av.w + adv.w)};
        if (i < DEGCAP) wlds[wv][i] = ev;
        m4.x = fmaxf(m4.x, ev.x); m4.y = fmaxf(m4.y, ev.y);
        m4.z = fmaxf(m4.z, ev.z); m4.w = fmaxf(m4.w, ev.w);
    }
#pragma unroll
    for (int msk = 1; msk < 64; msk <<= 1) {
        m4.x = fmaxf(m4.x, __shfl_xor(m4.x, msk));
        m4.y = fmaxf(m4.y, __shfl_xor(m4.y, msk));
        m4.z = fmaxf(m4.z, __shfl_xor(m4.z, msk));
        m4.w = fmaxf(m4.w, __shfl_xor(m4.w, msk));
    }
    float4 s4 = {0.f, 0.f, 0.f, 0.f};
    for (int i = lane; i < deg; i += 64) {
        float4 ev;
        if (i < DEGCAP) ev = wlds[wv][i];
        else {
            int s = clamp_node(csr_src[beg + i]);
            float4 av = a_s4[s];
            ev = {leaky(av.x + adv.x), leaky(av.y + adv.y),
                  leaky(av.z + adv.z), leaky(av.w + adv.w)};
        }
        float4 ex = {__expf(ev.x - m4.x), __expf(ev.y - m4.y),
                     __expf(ev.z - m4.z), __expf(ev.w - m4.w)};
        if (i < DEGCAP) wlds[wv][i] = ex;
        s4.x += ex.x; s4.y += ex.y; s4.z += ex.z; s4.w += ex.w;
    }
#pragma unroll
    for (int msk = 1; msk < 64; msk <<= 1) {
        s4.x += __shfl_xor(s4.x, msk);
        s4.y += __shfl_xor(s4.y, msk);
        s4.z += __shfl_xor(s4.z, msk);
        s4.w += __shfl_xor(s4.w, msk);
    }
    float4 exs = {__expf(ev_self.x - m4.x), __expf(ev_self.y - m4.y),
                  __expf(ev_self.z - m4.z), __expf(ev_self.w - m4.w)};
    s4.x += exs.x; s4.y += exs.y; s4.z += exs.z; s4.w += exs.w;

    float mh = selc(m4, h);
    float dh = selc(adv, h);
    float ih = 1.f / selc(s4, h);
    float wself = selc(exs, h);

    float accv[8];
#pragma unroll
    for (int j = 0; j < 8; ++j) accv[j] = wself * (float)xvself[j];

    const float* wrow = (const float*)&wlds[wv][0];
    for (int b0 = 0; b0 < deg; b0 += 8) {
        int cnt = deg - b0; if (cnt > 8) cnt = 8;
        bf16v8 xv[8]; float w8[8];
#pragma unroll
        for (int u = 0; u < 8; ++u) {
            if (u < cnt) {
                int e = b0 + u;
                int s = (e < 64) ? __shfl(s_reg, e) : clamp_node(csr_src[beg + e]);
                xv[u] = *reinterpret_cast<const bf16v8*>(xp + (size_t)s * HD + h * DIM + d0);
                w8[u] = (e < DEGCAP) ? wrow[e * 4 + h]
                                     : __expf(leaky(a_s[s * 4 + h] + dh) - mh);
            }
        }
#pragma unroll
        for (int u = 0; u < 8; ++u) {
            if (u < cnt) {
#pragma unroll
                for (int j = 0; j < 8; ++j) accv[j] += w8[u] * (float)xv[u][j];
            }
        }
    }
#pragma unroll
    for (int j = 0; j < 8; ++j) accv[j] *= ih;

#pragma unroll
    for (int j = 0; j < 8; ++j) {
        accv[j] += __shfl_xor(accv[j], 16);
        accv[j] += __shfl_xor(accv[j], 32);
        accv[j] *= 0.25f;
    }
    bf16v8 rv = *reinterpret_cast<const bf16v8*>(xres + (size_t)n * DIM + d0);
    bf16v8 bv = *reinterpret_cast<const bf16v8*>(bias + d0);
    float vals[8];
    float ss = 0.f;
#pragma unroll
    for (int j = 0; j < 8; ++j) {
        float v = accv[j] + (float)bv[j] + (float)rv[j];
        vals[j] = v;
        ss += v * v;
    }
    ss += __shfl_xor(ss, 1); ss += __shfl_xor(ss, 2);
    ss += __shfl_xor(ss, 4); ss += __shfl_xor(ss, 8);
    float scale = rsqrtf(ss * (1.f / 128.f) + EPS_RMS);
    if (h == 0) {
        bf16v8 nw = *reinterpret_cast<const bf16v8*>(normw + d0);
        bf16v8 ov;
#pragma unroll
        for (int j = 0; j < 8; ++j) ov[j] = (bf16_t)(vals[j] * scale * (float)nw[j]);
        *reinterpret_cast<bf16v8*>(out + (size_t)n * DIM + d0) = ov;
    }
}

// ---------------- fused FFN: out = rmsnorm(x + relu(x@W1+b1)@W2 + b2, nw) ----------------
// One wave = one 16-row tile, full 128 cols. h round-trips through wave-private
// LDS (C-layout -> A-layout), no barrier. OUTF32: final layer writes f32 d_out.
template <int OUTF32>
__global__ __launch_bounds__(256) void ffn_fused(const bf16_t* __restrict__ A,
                                                 const bf16_t* __restrict__ B1t,
                                                 const bf16_t* __restrict__ b1,
                                                 const bf16_t* __restrict__ B2t,
                                                 const bf16_t* __restrict__ b2,
                                                 const bf16_t* __restrict__ nw,
                                                 void* __restrict__ Cout) {
    __shared__ bf16_t hl[4][16 * 136];   // pad 136 halfwords/row
    int unit = (int)((blockIdx.x * blockDim.x + threadIdx.x) >> 6);
    if (unit >= NTILES) return;
    int lane = threadIdx.x & 63;
    int wv = threadIdx.x >> 6;
    int m = lane & 15, kq = lane >> 4;

    // GEMM1: h = relu(A @ W1 + b1)
    const bf16_t* Arow = A + (size_t)(unit * 16 + m) * DIM + kq * 8;
    bf16v8 a[4];
#pragma unroll
    for (int ks = 0; ks < 4; ++ks)
        a[ks] = *reinterpret_cast<const bf16v8*>(Arow + ks * 32);
    f32v4 acc[8];
#pragma unroll
    for (int t = 0; t < 8; ++t) acc[t] = (f32v4){0.f, 0.f, 0.f, 0.f};
    const bf16_t* Bb1 = B1t + (size_t)m * DIM + kq * 8;
#pragma unroll
    for (int ks = 0; ks < 4; ++ks) {
#pragma unroll
        for (int t = 0; t < 8; ++t) {
            bf16v8 b = *reinterpret_cast<const bf16v8*>(Bb1 + (size_t)t * 16 * DIM + ks * 32);
            acc[t] = __builtin_amdgcn_mfma_f32_16x16x32_bf16(a[ks], b, acc[t], 0, 0, 0);
        }
    }
    // h -> LDS (tile-local [row][col])
#pragma unroll
    for (int t = 0; t < 8; ++t) {
        int col = t * 16 + m;
        float bv = (float)b1[col];
#pragma unroll
        for (int r = 0; r < 4; ++r) {
            float v = acc[t][r] + bv;
            v = v > 0.f ? v : 0.f;
            hl[wv][(kq * 4 + r) * 136 + col] = (bf16_t)v;
        }
    }
    // A2-fragments from LDS (same wave; compiler inserts lgkmcnt)
    bf16v8 a2[4];
#pragma unroll
    for (int ks = 0; ks < 4; ++ks)
        a2[ks] = *reinterpret_cast<const bf16v8*>(&hl[wv][m * 136 + ks * 32 + kq * 8]);
    // GEMM2
    f32v4 acc2[8];
#pragma unroll
    for (int t = 0; t < 8; ++t) acc2[t] = (f32v4){0.f, 0.f, 0.f, 0.f};
    const bf16_t* Bb2 = B2t + (size_t)m * DIM + kq * 8;
#pragma unroll
    for (int ks = 0; ks < 4; ++ks) {
#pragma unroll
        for (int t = 0; t < 8; ++t) {
            bf16v8 b = *reinterpret_cast<const bf16v8*>(Bb2 + (size_t)t * 16 * DIM + ks * 32);
            acc2[t] = __builtin_amdgcn_mfma_f32_16x16x32_bf16(a2[ks], b, acc2[t], 0, 0, 0);
        }
    }
    // epilogue: rmsnorm(res + acc2 + b2) * nw
    int growbase = unit * 16 + kq * 4;
    float vals[8][4];
    float ssq[4] = {0.f, 0.f, 0.f, 0.f};
#pragma unroll
    for (int t = 0; t < 8; ++t) {
        int col = t * 16 + m;
        float bv = (float)b2[col];
#pragma unroll
        for (int r = 0; r < 4; ++r) {
            float v = acc2[t][r] + bv + (float)A[(size_t)(growbase + r) * DIM + col];
            vals[t][r] = v;
            ssq[r] += v * v;
        }
    }
#pragma unroll
    for (int r = 0; r < 4; ++r) {
        float s = ssq[r];
        s += __shfl_xor(s, 1);
        s += __shfl_xor(s, 2);
        s += __shfl_xor(s, 4);
        s += __shfl_xor(s, 8);
        ssq[r] = rsqrtf(s * (1.f / 128.f) + EPS_RMS);
    }
#pragma unroll
    for (int t = 0; t < 8; ++t) {
        int col = t * 16 + m;
        float nwv = (float)nw[col];
#pragma unroll
        for (int r = 0; r < 4; ++r) {
            float o = vals[t][r] * ssq[r] * nwv;
            if (OUTF32) ((float*)Cout)[(size_t)(growbase + r) * DIM + col] = o;
            else        ((bf16_t*)Cout)[(size_t)(growbase + r) * DIM + col] = (bf16_t)o;
        }
    }
}

// ---------------- launch ----------------
extern "C" void kernel_launch(void* const* d_in, const int* in_sizes, int n_in,
                              void* d_out, int out_size, void* d_ws, size_t ws_size,
                              hipStream_t stream) {
    const void* x_in   = d_in[0];
    const void* W_gat  = d_in[1];
    const void* att_s  = d_in[2];
    const void* att_d  = d_in[3];
    const void* bias_g = d_in[4];
    const void* W1     = d_in[5];
    const void* b1     = d_in[6];
    const void* W2     = d_in[7];
    const void* b2     = d_in[8];
    const void* n1w    = d_in[9];
    const void* n2w    = d_in[10];
    const int*  ei     = (const int*)d_in[11];

    char* ws = (char*)d_ws;
    size_t off = 0;
    auto alloc = [&](size_t bytes) {
        void* p = ws + off;
        off = (off + bytes + 255) & ~(size_t)255;
        return p;
    };
    bf16_t* WgT     = (bf16_t*)alloc((size_t)LAYERS * HD * DIM * 2);
    bf16_t* W1T     = (bf16_t*)alloc((size_t)LAYERS * DIM * DIM * 2);
    bf16_t* W2T     = (bf16_t*)alloc((size_t)LAYERS * DIM * DIM * 2);
    bf16_t* xb      = (bf16_t*)alloc((size_t)N_NODES * DIM * 2);
    bf16_t* xp      = (bf16_t*)alloc((size_t)N_NODES * HD * 2);
    float*  a_s     = (float*)alloc((size_t)N_NODES * NH * 4);
    float*  a_d     = (float*)alloc((size_t)N_NODES * NH * 4);
    int*    deg     = (int*)alloc((size_t)N_NODES * 4);
    int*    cursor  = (int*)alloc((size_t)N_NODES * 4);
    int*    row_ptr = (int*)alloc((size_t)(N_NODES + 1) * 4);
    int*    csr     = (int*)alloc((size_t)NEDGE * 4);
    bf16_t* xmid    = (bf16_t*)alloc((size_t)N_NODES * DIM * 2);
    bf16_t* attSc   = (bf16_t*)alloc((size_t)LAYERS * NH * DIM * 2);
    bf16_t* attDc   = (bf16_t*)alloc((size_t)LAYERS * NH * DIM * 2);
    bf16_t* bgc     = (bf16_t*)alloc((size_t)LAYERS * DIM * 2);
    bf16_t* b1c     = (bf16_t*)alloc((size_t)LAYERS * DIM * 2);
    bf16_t* b2c     = (bf16_t*)alloc((size_t)LAYERS * DIM * 2);
    bf16_t* n1c     = (bf16_t*)alloc((size_t)LAYERS * DIM * 2);
    bf16_t* n2c     = (bf16_t*)alloc((size_t)LAYERS * DIM * 2);

    hipMemsetAsync(deg, 0, (size_t)N_NODES * 4, stream);

    const int NTOT = N_NODES * DIM + LAYERS * DIM * HD + 2 * LAYERS * DIM * DIM
                   + 2 * LAYERS * NH * DIM + 5 * LAYERS * DIM;
    convert_all<<<(NTOT + 255) / 256, 256, 0, stream>>>(
        x_in, W_gat, W1, W2, att_s, att_d, bias_g, b1, b2, n1w, n2w,
        xb, WgT, W1T, W2T, attSc, attDc, bgc, b1c, b2c, n1c, n2c);

    hist_kernel<<<(NEDGE + 255) / 256, 256, 0, stream>>>(ei, deg);
    scan_kernel<<<1, 1024, 0, stream>>>(deg, row_ptr, cursor);
    fill_kernel<<<(NEDGE + 255) / 256, 256, 0, stream>>>(ei, cursor, csr);

    for (int l = 0; l < LAYERS; ++l) {
        gemm_att<<<dim3((NTILES + 3) / 4, 4), 256, 0, stream>>>(
            xb, WgT + (size_t)l * HD * DIM,
            attSc + (size_t)l * NH * DIM, attDc + (size_t)l * NH * DIM,
            a_s, a_d, xp);
        gat_agg<<<(N_NODES * 64 + 255) / 256, 256, 0, stream>>>(
            row_ptr, csr, a_s, a_d, xp, xb,
            bgc + (size_t)l * DIM, n1c + (size_t)l * DIM, xmid);
        if (l < LAYERS - 1) {
            ffn_fused<0><<<(NTILES + 3) / 4, 256, 0, stream>>>(
                xmid, W1T + (size_t)l * DIM * DIM, b1c + (size_t)l * DIM,
                W2T + (size_t)l * DIM * DIM, b2c + (size_t)l * DIM,
                n2c + (size_t)l * DIM, xb);
        } else {
            ffn_fused<1><<<(NTILES + 3) / 4, 256, 0, stream>>>(
                xmid, W1T + (size_t)l * DIM * DIM, b1c + (size_t)l * DIM,
                W2T + (size_t)l * DIM * DIM, b2c + (size_t)l * DIM,
                n2c + (size_t)l * DIM, d_out);
        }
    }
}

// Round 7
// 358.834 us; speedup vs baseline: 1.4728x; 1.1502x over previous
//
#include <hip/hip_runtime.h>
#include <hip/hip_bf16.h>

#define N_NODES 20000
#define NEDGE   320000
#define DIM     128
#define NH      4
#define HD      512   // NH*DIM
#define LAYERS  3
#define EPS_RMS 1.1920929e-07f
#define SLOPE   0.2f
#define DEGCAP  128
#define NTILES  (N_NODES >> 4)   // 1250

typedef __bf16 bf16_t;
typedef __bf16 bf16v8 __attribute__((ext_vector_type(8)));
typedef float  f32v4  __attribute__((ext_vector_type(4)));
typedef float  f32v2  __attribute__((ext_vector_type(2)));

__device__ __forceinline__ int clamp_node(int s) {
    return ((unsigned)s >= (unsigned)N_NODES) ? 0 : s;
}
__device__ __forceinline__ float leaky(float e) { return e > 0.f ? e : SLOPE * e; }
__device__ __forceinline__ float selc(float4 v, int h) {
    return h == 0 ? v.x : h == 1 ? v.y : h == 2 ? v.z : v.w;
}
// fp8 e4m3 encode (RNE, hardware)
__device__ __forceinline__ unsigned char enc_fp8(float v) {
    int p = __builtin_amdgcn_cvt_pk_fp8_f32(v, v, 0, false);
    return (unsigned char)(p & 0xff);
}

// ---- per-wave dtype detection ----
__device__ __forceinline__ bool wave_detect_bf16(const unsigned short* xh) {
    int lane = threadIdx.x & 63;
    unsigned short hw = xh[2 * lane];
    int e = (hw >> 7) & 0xff;
    unsigned long long b = __ballot(e >= 96 && e <= 140);
    return __popcll(b) >= 48;
}
__device__ __forceinline__ bool wave_detect_i64(const int* ei) {
    int lane = threadIdx.x & 63;
    unsigned long long b = __ballot(ei[2 * lane + 1] != 0);
    return b == 0ULL;
}
__device__ __forceinline__ bf16_t cvt_elem(const void* in, size_t j, bool isbf) {
    return isbf ? ((const bf16_t*)in)[j] : (bf16_t)((const float*)in)[j];
}
__device__ __forceinline__ int edge_src(const int* ei, int e, bool is64) {
    return clamp_node(is64 ? ei[2 * e] : ei[e]);
}
__device__ __forceinline__ int edge_dst(const int* ei, int e, bool is64) {
    return clamp_node(is64 ? ei[2 * NEDGE + 2 * e] : ei[NEDGE + e]);
}

// ---------------- canonicalization (+ hist fused as trailing blocks) ----------------
__global__ __launch_bounds__(256) void convert_hist(
        const void* x, const void* Wg, const void* W1, const void* W2,
        const void* aS, const void* aD, const void* bg, const void* b1,
        const void* b2, const void* n1, const void* n2,
        bf16_t* xb, bf16_t* WgT, bf16_t* W1T, bf16_t* W2T,
        bf16_t* aSc, bf16_t* aDc, bf16_t* bgc, bf16_t* b1c,
        bf16_t* b2c, bf16_t* n1c, bf16_t* n2c,
        const int* ei, int* deg, int convBlocks) {
    const int NX  = N_NODES * DIM;
    const int NWG = LAYERS * DIM * HD;
    const int NW1 = LAYERS * DIM * DIM;
    const int NSM = LAYERS * NH * DIM;
    const int NV  = LAYERS * DIM;
    if ((int)blockIdx.x >= convBlocks) {   // histogram part
        bool is64 = wave_detect_i64(ei);
        int e = ((int)blockIdx.x - convBlocks) * 256 + threadIdx.x;
        if (e < NEDGE) atomicAdd(&deg[edge_dst(ei, e, is64)], 1);
        return;
    }
    bool isbf = wave_detect_bf16((const unsigned short*)x);
    int i = blockIdx.x * blockDim.x + threadIdx.x;
    if (i < NX) { xb[i] = cvt_elem(x, i, isbf); return; }
    i -= NX;
    if (i < NWG) {  // WgT[l][c][k] = Wg[l][k][c]
        int l = i / (DIM * HD);
        int rem = i - l * (DIM * HD);
        int c = rem / DIM, k = rem - c * DIM;
        WgT[i] = cvt_elem(Wg, (size_t)l * DIM * HD + (size_t)k * HD + c, isbf);
        return;
    }
    i -= NWG;
    if (i < NW1) {
        int l = i / (DIM * DIM);
        int rem = i - l * (DIM * DIM);
        int c = rem / DIM, k = rem - c * DIM;
        W1T[i] = cvt_elem(W1, (size_t)l * DIM * DIM + (size_t)k * DIM + c, isbf);
        return;
    }
    i -= NW1;
    if (i < NW1) {
        int l = i / (DIM * DIM);
        int rem = i - l * (DIM * DIM);
        int c = rem / DIM, k = rem - c * DIM;
        W2T[i] = cvt_elem(W2, (size_t)l * DIM * DIM + (size_t)k * DIM + c, isbf);
        return;
    }
    i -= NW1;
    if (i < NSM) { aSc[i] = cvt_elem(aS, i, isbf); return; }
    i -= NSM;
    if (i < NSM) { aDc[i] = cvt_elem(aD, i, isbf); return; }
    i -= NSM;
    if (i >= 5 * NV) return;
    int seg = i / NV, k = i - seg * NV;
    if (seg == 0) bgc[k] = cvt_elem(bg, k, isbf);
    else if (seg == 1) b1c[k] = cvt_elem(b1, k, isbf);
    else if (seg == 2) b2c[k] = cvt_elem(b2, k, isbf);
    else if (seg == 3) n1c[k] = cvt_elem(n1, k, isbf);
    else n2c[k] = cvt_elem(n2, k, isbf);
}

__global__ __launch_bounds__(1024) void scan_kernel(const int* __restrict__ deg,
                                                    int* __restrict__ row_ptr,
                                                    int* __restrict__ cursor) {
    __shared__ int wsum[16];
    __shared__ int carry_s;
    int tid = threadIdx.x, lane = tid & 63, wv = tid >> 6;
    if (tid == 0) { carry_s = 0; row_ptr[0] = 0; }
    __syncthreads();
    for (int base = 0; base < N_NODES; base += 1024) {
        int idx = base + tid;
        int v = (idx < N_NODES) ? deg[idx] : 0;
        int x = v;
#pragma unroll
        for (int off = 1; off < 64; off <<= 1) {
            int t = __shfl_up(x, off);
            if (lane >= off) x += t;
        }
        if (lane == 63) wsum[wv] = x;
        __syncthreads();
        if (wv == 0) {
            int s = (lane < 16) ? wsum[lane] : 0;
#pragma unroll
            for (int off = 1; off < 16; off <<= 1) {
                int t = __shfl_up(s, off);
                if (lane >= off) s += t;
            }
            if (lane < 16) wsum[lane] = s;
        }
        __syncthreads();
        int woff = (wv == 0) ? 0 : wsum[wv - 1];
        int c = carry_s;
        int incl = x + woff + c;
        if (idx < N_NODES) {
            row_ptr[idx + 1] = incl;
            cursor[idx] = incl - v;
        }
        __syncthreads();
        if (tid == 1023) carry_s = incl;
        __syncthreads();
    }
}

__global__ void fill_kernel(const int* __restrict__ ei, int* __restrict__ cursor,
                            int* __restrict__ csr_src) {
    bool is64 = wave_detect_i64(ei);
    int e = blockIdx.x * blockDim.x + threadIdx.x;
    if (e < NEDGE) {
        int d = edge_dst(ei, e, is64);
        int pos = atomicAdd(&cursor[d], 1);
        if ((unsigned)pos < (unsigned)NEDGE) csr_src[pos] = edge_src(ei, e, is64);
    }
}

// ---------------- attention GEMM: xp(fp8) = x @ Wg, fused a_s/a_d epilogue ----------------
__global__ __launch_bounds__(256) void gemm_att(const bf16_t* __restrict__ A,
                                                const bf16_t* __restrict__ Bt,
                                                const bf16_t* __restrict__ attS,
                                                const bf16_t* __restrict__ attD,
                                                float* __restrict__ aSg,
                                                float* __restrict__ aDg,
                                                unsigned char* __restrict__ xp8) {
    __shared__ bf16_t bl[128 * 132];
    int wv = threadIdx.x >> 6;
    int lane = threadIdx.x & 63;
    int m = lane & 15, kq = lane >> 4;
    int colbase = blockIdx.y << 7;

    const bf16_t* Bsrc = Bt + (size_t)colbase * DIM;
#pragma unroll
    for (int it = 0; it < 8; ++it) {
        int chunk = it * 256 + threadIdx.x;
        int c = chunk >> 4, ko = (chunk & 15) * 8;
        *reinterpret_cast<bf16v8*>(&bl[c * 132 + ko]) =
            *reinterpret_cast<const bf16v8*>(&Bsrc[c * DIM + ko]);
    }
    __syncthreads();

    int row16 = blockIdx.x * 4 + wv;
    if (row16 >= NTILES) return;

    const bf16_t* Arow = A + (size_t)(row16 * 16 + m) * DIM + kq * 8;
    bf16v8 a[4];
#pragma unroll
    for (int ks = 0; ks < 4; ++ks)
        a[ks] = *reinterpret_cast<const bf16v8*>(Arow + ks * 32);

    f32v4 acc[8];
#pragma unroll
    for (int t = 0; t < 8; ++t) acc[t] = (f32v4){0.f, 0.f, 0.f, 0.f};
#pragma unroll
    for (int ks = 0; ks < 4; ++ks) {
#pragma unroll
        for (int t = 0; t < 8; ++t) {
            bf16v8 b = *reinterpret_cast<const bf16v8*>(&bl[(t * 16 + m) * 132 + ks * 32 + kq * 8]);
            acc[t] = __builtin_amdgcn_mfma_f32_16x16x32_bf16(a[ks], b, acc[t], 0, 0, 0);
        }
    }

    int growbase = row16 * 16 + kq * 4;
    int hh = blockIdx.y;
    float as8[8], ad8[8];
#pragma unroll
    for (int t = 0; t < 8; ++t) {
        as8[t] = (float)attS[hh * DIM + t * 16 + m];
        ad8[t] = (float)attD[hh * DIM + t * 16 + m];
    }
#pragma unroll
    for (int r = 0; r < 4; ++r) {
        float ps = 0.f, pd = 0.f;
#pragma unroll
        for (int t = 0; t < 8; ++t) {
            ps += acc[t][r] * as8[t];
            pd += acc[t][r] * ad8[t];
        }
        ps += __shfl_xor(ps, 1); ps += __shfl_xor(ps, 2);
        ps += __shfl_xor(ps, 4); ps += __shfl_xor(ps, 8);
        pd += __shfl_xor(pd, 1); pd += __shfl_xor(pd, 2);
        pd += __shfl_xor(pd, 4); pd += __shfl_xor(pd, 8);
        if (m == 0) {
            int row = growbase + r;
            aSg[row * 4 + hh] = ps;
            aDg[row * 4 + hh] = pd;
        }
    }
#pragma unroll
    for (int t = 0; t < 8; ++t) {
        int col = colbase + t * 16 + m;
#pragma unroll
        for (int r = 0; r < 4; ++r)
            xp8[(size_t)(growbase + r) * HD + col] = enc_fp8(acc[t][r]);
    }
}

// ---------------- GAT aggregate (fp8 xp) + head-mean + bias + residual + rmsnorm ----------------
__global__ __launch_bounds__(256) void gat_agg(const int* __restrict__ row_ptr,
                                               const int* __restrict__ csr_src,
                                               const float* __restrict__ a_s,
                                               const float* __restrict__ a_d,
                                               const unsigned char* __restrict__ xp8,
                                               const bf16_t* __restrict__ xres,
                                               const bf16_t* __restrict__ bias,
                                               const bf16_t* __restrict__ normw,
                                               bf16_t* __restrict__ out) {
    __shared__ float4 wlds[4][DEGCAP];
    int n = (int)((blockIdx.x * blockDim.x + threadIdx.x) >> 6);
    if (n >= N_NODES) return;
    int lane = threadIdx.x & 63;
    int wv = threadIdx.x >> 6;
    int beg = row_ptr[n];
    int deg = row_ptr[n + 1] - beg;
    if (deg < 0) deg = 0;
    if (deg > NEDGE) deg = NEDGE;
    if (beg < 0) beg = 0;
    if (beg > NEDGE - deg) beg = NEDGE - deg;

    const float4* a_s4 = reinterpret_cast<const float4*>(a_s);
    const float4 adv = reinterpret_cast<const float4*>(a_d)[n];
    const float4 avs = a_s4[n];
    int h = lane >> 4;
    int d0 = (lane & 15) * 8;
    uint2 pself = *reinterpret_cast<const uint2*>(xp8 + (size_t)n * HD + h * DIM + d0);
    int s_reg = (lane < deg) ? clamp_node(csr_src[beg + lane]) : n;

    float4 ev_self = {leaky(avs.x + adv.x), leaky(avs.y + adv.y),
                      leaky(avs.z + adv.z), leaky(avs.w + adv.w)};

    float4 m4 = ev_self;
    for (int i = lane; i < deg; i += 64) {
        int s = (i == lane) ? s_reg : clamp_node(csr_src[beg + i]);
        float4 av = a_s4[s];
        float4 ev = {leaky(av.x + adv.x), leaky(av.y + adv.y),
                     leaky(av.z + adv.z), leaky(av.w + adv.w)};
        if (i < DEGCAP) wlds[wv][i] = ev;
        m4.x = fmaxf(m4.x, ev.x); m4.y = fmaxf(m4.y, ev.y);
        m4.z = fmaxf(m4.z, ev.z); m4.w = fmaxf(m4.w, ev.w);
    }
#pragma unroll
    for (int msk = 1; msk < 64; msk <<= 1) {
        m4.x = fmaxf(m4.x, __shfl_xor(m4.x, msk));
        m4.y = fmaxf(m4.y, __shfl_xor(m4.y, msk));
        m4.z = fmaxf(m4.z, __shfl_xor(m4.z, msk));
        m4.w = fmaxf(m4.w, __shfl_xor(m4.w, msk));
    }
    float4 s4 = {0.f, 0.f, 0.f, 0.f};
    for (int i = lane; i < deg; i += 64) {
        float4 ev;
        if (i < DEGCAP) ev = wlds[wv][i];
        else {
            int s = clamp_node(csr_src[beg + i]);
            float4 av = a_s4[s];
            ev = {leaky(av.x + adv.x), leaky(av.y + adv.y),
                  leaky(av.z + adv.z), leaky(av.w + adv.w)};
        }
        float4 ex = {__expf(ev.x - m4.x), __expf(ev.y - m4.y),
                     __expf(ev.z - m4.z), __expf(ev.w - m4.w)};
        if (i < DEGCAP) wlds[wv][i] = ex;
        s4.x += ex.x; s4.y += ex.y; s4.z += ex.z; s4.w += ex.w;
    }
#pragma unroll
    for (int msk = 1; msk < 64; msk <<= 1) {
        s4.x += __shfl_xor(s4.x, msk);
        s4.y += __shfl_xor(s4.y, msk);
        s4.z += __shfl_xor(s4.z, msk);
        s4.w += __shfl_xor(s4.w, msk);
    }
    float4 exs = {__expf(ev_self.x - m4.x), __expf(ev_self.y - m4.y),
                  __expf(ev_self.z - m4.z), __expf(ev_self.w - m4.w)};
    s4.x += exs.x; s4.y += exs.y; s4.z += exs.z; s4.w += exs.w;

    float mh = selc(m4, h);
    float dh = selc(adv, h);
    float ih = 1.f / selc(s4, h);
    float wself = selc(exs, h);

    float accv[8];
    {
        f32v2 f0 = __builtin_amdgcn_cvt_pk_f32_fp8((int)pself.x, false);
        f32v2 f1 = __builtin_amdgcn_cvt_pk_f32_fp8((int)pself.x, true);
        f32v2 f2 = __builtin_amdgcn_cvt_pk_f32_fp8((int)pself.y, false);
        f32v2 f3 = __builtin_amdgcn_cvt_pk_f32_fp8((int)pself.y, true);
        accv[0] = wself * f0[0]; accv[1] = wself * f0[1];
        accv[2] = wself * f1[0]; accv[3] = wself * f1[1];
        accv[4] = wself * f2[0]; accv[5] = wself * f2[1];
        accv[6] = wself * f3[0]; accv[7] = wself * f3[1];
    }

    const float* wrow = (const float*)&wlds[wv][0];
    for (int b0 = 0; b0 < deg; b0 += 8) {
        int cnt = deg - b0; if (cnt > 8) cnt = 8;
        uint2 xv[8]; float w8[8];
#pragma unroll
        for (int u = 0; u < 8; ++u) {
            if (u < cnt) {
                int e = b0 + u;
                int s = (e < 64) ? __shfl(s_reg, e) : clamp_node(csr_src[beg + e]);
                xv[u] = *reinterpret_cast<const uint2*>(xp8 + (size_t)s * HD + h * DIM + d0);
                w8[u] = (e < DEGCAP) ? wrow[e * 4 + h]
                                     : __expf(leaky(a_s[s * 4 + h] + dh) - mh);
            }
        }
#pragma unroll
        for (int u = 0; u < 8; ++u) {
            if (u < cnt) {
                f32v2 f0 = __builtin_amdgcn_cvt_pk_f32_fp8((int)xv[u].x, false);
                f32v2 f1 = __builtin_amdgcn_cvt_pk_f32_fp8((int)xv[u].x, true);
                f32v2 f2 = __builtin_amdgcn_cvt_pk_f32_fp8((int)xv[u].y, false);
                f32v2 f3 = __builtin_amdgcn_cvt_pk_f32_fp8((int)xv[u].y, true);
                float w = w8[u];
                accv[0] += w * f0[0]; accv[1] += w * f0[1];
                accv[2] += w * f1[0]; accv[3] += w * f1[1];
                accv[4] += w * f2[0]; accv[5] += w * f2[1];
                accv[6] += w * f3[0]; accv[7] += w * f3[1];
            }
        }
    }
#pragma unroll
    for (int j = 0; j < 8; ++j) accv[j] *= ih;

#pragma unroll
    for (int j = 0; j < 8; ++j) {
        accv[j] += __shfl_xor(accv[j], 16);
        accv[j] += __shfl_xor(accv[j], 32);
        accv[j] *= 0.25f;
    }
    bf16v8 rv = *reinterpret_cast<const bf16v8*>(xres + (size_t)n * DIM + d0);
    bf16v8 bv = *reinterpret_cast<const bf16v8*>(bias + d0);
    float vals[8];
    float ss = 0.f;
#pragma unroll
    for (int j = 0; j < 8; ++j) {
        float v = accv[j] + (float)bv[j] + (float)rv[j];
        vals[j] = v;
        ss += v * v;
    }
    ss += __shfl_xor(ss, 1); ss += __shfl_xor(ss, 2);
    ss += __shfl_xor(ss, 4); ss += __shfl_xor(ss, 8);
    float scale = rsqrtf(ss * (1.f / 128.f) + EPS_RMS);
    if (h == 0) {
        bf16v8 nw = *reinterpret_cast<const bf16v8*>(normw + d0);
        bf16v8 ov;
#pragma unroll
        for (int j = 0; j < 8; ++j) ov[j] = (bf16_t)(vals[j] * scale * (float)nw[j]);
        *reinterpret_cast<bf16v8*>(out + (size_t)n * HD / 4 + d0) = ov;  // HD/4 == DIM
    }
}

// ---------------- fused FFN ----------------
template <int OUTF32>
__global__ __launch_bounds__(256) void ffn_fused(const bf16_t* __restrict__ A,
                                                 const bf16_t* __restrict__ B1t,
                                                 const bf16_t* __restrict__ b1,
                                                 const bf16_t* __restrict__ B2t,
                                                 const bf16_t* __restrict__ b2,
                                                 const bf16_t* __restrict__ nw,
                                                 void* __restrict__ Cout) {
    __shared__ bf16_t hl[4][16 * 136];
    int unit = (int)((blockIdx.x * blockDim.x + threadIdx.x) >> 6);
    if (unit >= NTILES) return;
    int lane = threadIdx.x & 63;
    int wv = threadIdx.x >> 6;
    int m = lane & 15, kq = lane >> 4;

    const bf16_t* Arow = A + (size_t)(unit * 16 + m) * DIM + kq * 8;
    bf16v8 a[4];
#pragma unroll
    for (int ks = 0; ks < 4; ++ks)
        a[ks] = *reinterpret_cast<const bf16v8*>(Arow + ks * 32);
    f32v4 acc[8];
#pragma unroll
    for (int t = 0; t < 8; ++t) acc[t] = (f32v4){0.f, 0.f, 0.f, 0.f};
    const bf16_t* Bb1 = B1t + (size_t)m * DIM + kq * 8;
#pragma unroll
    for (int ks = 0; ks < 4; ++ks) {
#pragma unroll
        for (int t = 0; t < 8; ++t) {
            bf16v8 b = *reinterpret_cast<const bf16v8*>(Bb1 + (size_t)t * 16 * DIM + ks * 32);
            acc[t] = __builtin_amdgcn_mfma_f32_16x16x32_bf16(a[ks], b, acc[t], 0, 0, 0);
        }
    }
#pragma unroll
    for (int t = 0; t < 8; ++t) {
        int col = t * 16 + m;
        float bv = (float)b1[col];
#pragma unroll
        for (int r = 0; r < 4; ++r) {
            float v = acc[t][r] + bv;
            v = v > 0.f ? v : 0.f;
            hl[wv][(kq * 4 + r) * 136 + col] = (bf16_t)v;
        }
    }
    bf16v8 a2[4];
#pragma unroll
    for (int ks = 0; ks < 4; ++ks)
        a2[ks] = *reinterpret_cast<const bf16v8*>(&hl[wv][m * 136 + ks * 32 + kq * 8]);
    f32v4 acc2[8];
#pragma unroll
    for (int t = 0; t < 8; ++t) acc2[t] = (f32v4){0.f, 0.f, 0.f, 0.f};
    const bf16_t* Bb2 = B2t + (size_t)m * DIM + kq * 8;
#pragma unroll
    for (int ks = 0; ks < 4; ++ks) {
#pragma unroll
        for (int t = 0; t < 8; ++t) {
            bf16v8 b = *reinterpret_cast<const bf16v8*>(Bb2 + (size_t)t * 16 * DIM + ks * 32);
            acc2[t] = __builtin_amdgcn_mfma_f32_16x16x32_bf16(a2[ks], b, acc2[t], 0, 0, 0);
        }
    }
    int growbase = unit * 16 + kq * 4;
    float vals[8][4];
    float ssq[4] = {0.f, 0.f, 0.f, 0.f};
#pragma unroll
    for (int t = 0; t < 8; ++t) {
        int col = t * 16 + m;
        float bv = (float)b2[col];
#pragma unroll
        for (int r = 0; r < 4; ++r) {
            float v = acc2[t][r] + bv + (float)A[(size_t)(growbase + r) * DIM + col];
            vals[t][r] = v;
            ssq[r] += v * v;
        }
    }
#pragma unroll
    for (int r = 0; r < 4; ++r) {
        float s = ssq[r];
        s += __shfl_xor(s, 1);
        s += __shfl_xor(s, 2);
        s += __shfl_xor(s, 4);
        s += __shfl_xor(s, 8);
        ssq[r] = rsqrtf(s * (1.f / 128.f) + EPS_RMS);
    }
#pragma unroll
    for (int t = 0; t < 8; ++t) {
        int col = t * 16 + m;
        float nwv = (float)nw[col];
#pragma unroll
        for (int r = 0; r < 4; ++r) {
            float o = vals[t][r] * ssq[r] * nwv;
            if (OUTF32) ((float*)Cout)[(size_t)(growbase + r) * DIM + col] = o;
            else        ((bf16_t*)Cout)[(size_t)(growbase + r) * DIM + col] = (bf16_t)o;
        }
    }
}

// ---------------- launch ----------------
extern "C" void kernel_launch(void* const* d_in, const int* in_sizes, int n_in,
                              void* d_out, int out_size, void* d_ws, size_t ws_size,
                              hipStream_t stream) {
    const void* x_in   = d_in[0];
    const void* W_gat  = d_in[1];
    const void* att_s  = d_in[2];
    const void* att_d  = d_in[3];
    const void* bias_g = d_in[4];
    const void* W1     = d_in[5];
    const void* b1     = d_in[6];
    const void* W2     = d_in[7];
    const void* b2     = d_in[8];
    const void* n1w    = d_in[9];
    const void* n2w    = d_in[10];
    const int*  ei     = (const int*)d_in[11];

    char* ws = (char*)d_ws;
    size_t off = 0;
    auto alloc = [&](size_t bytes) {
        void* p = ws + off;
        off = (off + bytes + 255) & ~(size_t)255;
        return p;
    };
    bf16_t* WgT     = (bf16_t*)alloc((size_t)LAYERS * HD * DIM * 2);
    bf16_t* W1T     = (bf16_t*)alloc((size_t)LAYERS * DIM * DIM * 2);
    bf16_t* W2T     = (bf16_t*)alloc((size_t)LAYERS * DIM * DIM * 2);
    bf16_t* xb      = (bf16_t*)alloc((size_t)N_NODES * DIM * 2);
    unsigned char* xp8 = (unsigned char*)alloc((size_t)N_NODES * HD);
    float*  a_s     = (float*)alloc((size_t)N_NODES * NH * 4);
    float*  a_d     = (float*)alloc((size_t)N_NODES * NH * 4);
    int*    deg     = (int*)alloc((size_t)N_NODES * 4);
    int*    cursor  = (int*)alloc((size_t)N_NODES * 4);
    int*    row_ptr = (int*)alloc((size_t)(N_NODES + 1) * 4);
    int*    csr     = (int*)alloc((size_t)NEDGE * 4);
    bf16_t* xmid    = (bf16_t*)alloc((size_t)N_NODES * DIM * 2);
    bf16_t* attSc   = (bf16_t*)alloc((size_t)LAYERS * NH * DIM * 2);
    bf16_t* attDc   = (bf16_t*)alloc((size_t)LAYERS * NH * DIM * 2);
    bf16_t* bgc     = (bf16_t*)alloc((size_t)LAYERS * DIM * 2);
    bf16_t* b1c     = (bf16_t*)alloc((size_t)LAYERS * DIM * 2);
    bf16_t* b2c     = (bf16_t*)alloc((size_t)LAYERS * DIM * 2);
    bf16_t* n1c     = (bf16_t*)alloc((size_t)LAYERS * DIM * 2);
    bf16_t* n2c     = (bf16_t*)alloc((size_t)LAYERS * DIM * 2);

    hipMemsetAsync(deg, 0, (size_t)N_NODES * 4, stream);

    const int NTOT = N_NODES * DIM + LAYERS * DIM * HD + 2 * LAYERS * DIM * DIM
                   + 2 * LAYERS * NH * DIM + 5 * LAYERS * DIM;
    const int convBlocks = (NTOT + 255) / 256;
    const int histBlocks = (NEDGE + 255) / 256;
    convert_hist<<<convBlocks + histBlocks, 256, 0, stream>>>(
        x_in, W_gat, W1, W2, att_s, att_d, bias_g, b1, b2, n1w, n2w,
        xb, WgT, W1T, W2T, attSc, attDc, bgc, b1c, b2c, n1c, n2c,
        ei, deg, convBlocks);

    scan_kernel<<<1, 1024, 0, stream>>>(deg, row_ptr, cursor);
    fill_kernel<<<(NEDGE + 255) / 256, 256, 0, stream>>>(ei, cursor, csr);

    for (int l = 0; l < LAYERS; ++l) {
        gemm_att<<<dim3((NTILES + 3) / 4, 4), 256, 0, stream>>>(
            xb, WgT + (size_t)l * HD * DIM,
            attSc + (size_t)l * NH * DIM, attDc + (size_t)l * NH * DIM,
            a_s, a_d, xp8);
        gat_agg<<<(N_NODES * 64 + 255) / 256, 256, 0, stream>>>(
            row_ptr, csr, a_s, a_d, xp8, xb,
            bgc + (size_t)l * DIM, n1c + (size_t)l * DIM, xmid);
        if (l < LAYERS - 1) {
            ffn_fused<0><<<(NTILES + 3) / 4, 256, 0, stream>>>(
                xmid, W1T + (size_t)l * DIM * DIM, b1c + (size_t)l * DIM,
                W2T + (size_t)l * DIM * DIM, b2c + (size_t)l * DIM,
                n2c + (size_t)l * DIM, xb);
        } else {
            ffn_fused<1><<<(NTILES + 3) / 4, 256, 0, stream>>>(
                xmid, W1T + (size_t)l * DIM * DIM, b1c + (size_t)l * DIM,
                W2T + (size_t)l * DIM * DIM, b2c + (size_t)l * DIM,
                n2c + (size_t)l * DIM, d_out);
        }
    }
}